// Round 8
// baseline (235.131 us; speedup 1.0000x reference)
//
#include <hip/hip_runtime.h>
#include <hip/hip_bf16.h>

// DRSA temporal block. B=2, P=8, hp=8, W=24, C=256, NH=8, dk=32, kv=4, H=64.
// 3072 positions, [pos][256] row-major. All GEMM-shaped work on bf16 MFMA.
// 11 dispatches: wtrans7, wtrans, qkloc2, topk, gemm_btx3, addkv_pad2,
// gemm_bt3, attn_mfma2 (inline V-transpose), gemm_wo_ln (merge+wo+LN1),
// conv_mfma4 (640 blocks for TLP), ln2_fused.

#define NPOS 3072
#define CD   256
#define NE   (NPOS*CD)

typedef short bf16x8 __attribute__((ext_vector_type(8)));
typedef float f32x4  __attribute__((ext_vector_type(4)));

__device__ inline ushort f2bf(float f) {
    __hip_bfloat16 h = __float2bfloat16(f);   // RNE
    return *reinterpret_cast<ushort*>(&h);
}
__device__ inline float bf2f(ushort u) {
    unsigned v = ((unsigned)u) << 16;
    return *reinterpret_cast<float*>(&v);
}

// ---------------------------------------------------------------- 7 weight transposes -> bf16
__global__ __launch_bounds__(256) void wtrans7(
    const float* __restrict__ w0, const float* __restrict__ w1, const float* __restrict__ w2,
    const float* __restrict__ w3, const float* __restrict__ w4, const float* __restrict__ w5,
    const float* __restrict__ w6, ushort* __restrict__ wt)
{
    __shared__ float l[64*65];
    int mat = blockIdx.y;
    const float* Wm = mat==0?w0:mat==1?w1:mat==2?w2:mat==3?w3:mat==4?w4:mat==5?w5:w6;
    int r2 = blockIdx.x;
    int ci0 = (r2 >> 2)*64, co0 = (r2 & 3)*64;
    int tid = threadIdx.x, a = tid >> 6, c = tid & 63;
    #pragma unroll 4
    for (int k = 0; k < 16; ++k) {
        int cil = k*4 + a;
        l[cil*65 + c] = Wm[(size_t)(ci0 + cil)*256 + co0 + c];
    }
    __syncthreads();
    #pragma unroll 4
    for (int k = 0; k < 16; ++k) {
        int col = k*4 + a;
        wt[(size_t)mat*65536 + ((size_t)(co0 + col))*256 + ci0 + c] = f2bf(l[c*65 + col]);
    }
}

// ---------------------------------------------------------------- conv weight transpose
__global__ __launch_bounds__(256) void wtrans(
    const float* __restrict__ cw, ushort* __restrict__ wct)
{
    __shared__ float l[64*65];
    int blk = blockIdx.x;
    int tap = blk >> 4;
    int r2  = blk & 15;
    int ci0 = (r2 >> 2) * 64;
    int co0 = (r2 & 3) * 64;
    int tid = threadIdx.x;
    int a = tid >> 6;
    int c = tid & 63;
    #pragma unroll 4
    for (int k = 0; k < 16; ++k) {
        int cil = k*4 + a;
        l[cil*65 + c] = cw[(size_t)tap*65536 + (size_t)(ci0 + cil)*256 + co0 + c];
    }
    __syncthreads();
    #pragma unroll 4
    for (int k = 0; k < 16; ++k) {
        int col = k*4 + a;
        wct[((size_t)(tap*256 + co0 + col))*256 + ci0 + c] = f2bf(l[c*65 + col]);
    }
}

// ---------------------------------------------------------------- fused xmean + q/k_loc [fp32 exact]
__global__ __launch_bounds__(256) void qkloc2(
    const float* __restrict__ x,
    const float* __restrict__ wq, const float* __restrict__ bq,
    const float* __restrict__ wk, const float* __restrict__ bk,
    float* __restrict__ qloc, float* __restrict__ kloc)
{
    __shared__ float xs[256];
    int bp = blockIdx.x, c = threadIdx.x;
    float s = 0.f;
    for (int i = 0; i < 192; ++i)
        s += x[((size_t)(bp*192 + i))*256 + c];
    xs[c] = s * (1.0f/192.0f);      // identical to xmean's sum-then-scale
    __syncthreads();
    const float* W  = blockIdx.y ? wk : wq;
    const float* Bv = blockIdx.y ? bk : bq;
    float* dst      = blockIdx.y ? kloc : qloc;
    float acc = Bv[c];
    #pragma unroll 8
    for (int k = 0; k < 256; ++k)
        acc += xs[k] * W[(size_t)k*256 + c];
    dst[bp*256 + c] = acc;
}

// ---------------------------------------------------------------- routing top-k (fp32 exact)
__global__ void topk_kern(const float* __restrict__ qloc, const float* __restrict__ kloc,
                          int* __restrict__ Rix)
{
    __shared__ float S[64];
    int b = blockIdx.x, t = threadIdx.x;
    int p = t >> 3, qq = t & 7;
    float s = 0.f;
    for (int c = 0; c < 256; ++c)
        s += qloc[(b*8+p)*256 + c] * kloc[(b*8+qq)*256 + c];
    S[t] = s;
    __syncthreads();
    if (t < 8) {
        float vals[8];
        #pragma unroll
        for (int j = 0; j < 8; ++j) vals[j] = S[t*8 + j];
        for (int j = 0; j < 4; ++j) {
            int best = 0; float bv = vals[0];
            #pragma unroll
            for (int i = 1; i < 8; ++i) if (vals[i] > bv) { bv = vals[i]; best = i; }
            Rix[(b*8 + t)*4 + j] = best;
            vals[best] = -1e30f;
        }
    }
}

// ---------------------------------------------------------------- bf16 MFMA GEMM triple, fp32 A
__global__ __launch_bounds__(256) void gemm_btx3(
    const float* __restrict__ A,
    const ushort* __restrict__ T0, const ushort* __restrict__ T1, const ushort* __restrict__ T2,
    const float* __restrict__ B0, const float* __restrict__ B1, const float* __restrict__ B2,
    ushort* __restrict__ U0, ushort* __restrict__ U1, ushort* __restrict__ U2)
{
    __shared__ __align__(16) ushort As[32*264];
    int y = blockIdx.y;
    const ushort* T = y==0 ? T0 : (y==1 ? T1 : T2);
    const float* Bi = y==0 ? B0 : (y==1 ? B1 : B2);
    ushort* U = y==0 ? U0 : (y==1 ? U1 : U2);
    int tid = threadIdx.x;
    int m0 = blockIdx.x*32;
    #pragma unroll
    for (int i = 0; i < 4; ++i) {
        int c = i*256 + tid;
        int pos = c >> 5, off = (c & 31)*8;
        const float* src = A + (size_t)(m0 + pos)*256 + off;
        float4 v0 = *(const float4*)src;
        float4 v1 = *(const float4*)(src + 4);
        ushort4 o0, o1;
        o0.x = f2bf(v0.x); o0.y = f2bf(v0.y); o0.z = f2bf(v0.z); o0.w = f2bf(v0.w);
        o1.x = f2bf(v1.x); o1.y = f2bf(v1.y); o1.z = f2bf(v1.z); o1.w = f2bf(v1.w);
        *(ushort4*)&As[pos*264 + off]     = o0;
        *(ushort4*)&As[pos*264 + off + 4] = o1;
    }
    __syncthreads();
    int w = tid >> 6, lane = tid & 63, lm = lane & 15, lq = lane >> 4;
    const ushort* tb = T + ((size_t)(w*64 + lm))*256 + lq*8;

    f32x4 acc[2][4];
    #pragma unroll
    for (int mt = 0; mt < 2; ++mt)
        #pragma unroll
        for (int nt = 0; nt < 4; ++nt) acc[mt][nt] = (f32x4){0.f,0.f,0.f,0.f};

    bf16x8 bw[4];
    #pragma unroll
    for (int nt = 0; nt < 4; ++nt) bw[nt] = *(const bf16x8*)(tb + nt*4096);

    for (int kc = 0; kc < 8; ++kc) {
        int nk = (kc + 1 < 8) ? kc + 1 : 7;
        bf16x8 bn[4];
        #pragma unroll
        for (int nt = 0; nt < 4; ++nt) bn[nt] = *(const bf16x8*)(tb + nt*4096 + nk*32);
        bf16x8 af[2];
        #pragma unroll
        for (int mt = 0; mt < 2; ++mt)
            af[mt] = *(const bf16x8*)&As[(mt*16 + lm)*264 + kc*32 + lq*8];
        #pragma unroll
        for (int mt = 0; mt < 2; ++mt)
            #pragma unroll
            for (int nt = 0; nt < 4; ++nt)
                acc[mt][nt] = __builtin_amdgcn_mfma_f32_16x16x32_bf16(af[mt], bw[nt], acc[mt][nt], 0,0,0);
        #pragma unroll
        for (int nt = 0; nt < 4; ++nt) bw[nt] = bn[nt];
    }

    #pragma unroll
    for (int mt = 0; mt < 2; ++mt) {
        #pragma unroll
        for (int nt = 0; nt < 4; ++nt) {
            int n = w*64 + nt*16 + lm;
            float bb = Bi[n];
            #pragma unroll
            for (int j = 0; j < 4; ++j) {
                int m = m0 + mt*16 + lq*4 + j;
                U[(size_t)m*256 + n] = f2bf(acc[mt][nt][j] + bb);
            }
        }
    }
}

// ---------------------------------------------------------------- bf16 MFMA GEMM triple, bf16 A
__global__ __launch_bounds__(256) void gemm_bt3(
    const ushort* __restrict__ A0, const ushort* __restrict__ A1, const ushort* __restrict__ A2,
    const ushort* __restrict__ T0, const ushort* __restrict__ T1, const ushort* __restrict__ T2,
    const float* __restrict__ B0, const float* __restrict__ B1, const float* __restrict__ B2,
    ushort* __restrict__ U0, ushort* __restrict__ U1, ushort* __restrict__ U2,
    float s0, float s1, float s2)
{
    __shared__ __align__(16) ushort As[32*264];
    int y = blockIdx.y;
    const ushort* A = y==0 ? A0 : (y==1 ? A1 : A2);
    const ushort* T = y==0 ? T0 : (y==1 ? T1 : T2);
    const float* Bi = y==0 ? B0 : (y==1 ? B1 : B2);
    ushort* U = y==0 ? U0 : (y==1 ? U1 : U2);
    float  sc = y==0 ? s0 : (y==1 ? s1 : s2);
    int tid = threadIdx.x;
    int m0 = blockIdx.x*32;
    #pragma unroll
    for (int i = 0; i < 4; ++i) {
        int c = i*256 + tid;
        int pos = c >> 5, off = (c & 31)*8;
        *(bf16x8*)&As[pos*264 + off] = *(const bf16x8*)(A + (size_t)(m0 + pos)*256 + off);
    }
    __syncthreads();
    int w = tid >> 6, lane = tid & 63, lm = lane & 15, lq = lane >> 4;
    const ushort* tb = T + ((size_t)(w*64 + lm))*256 + lq*8;

    f32x4 acc[2][4];
    #pragma unroll
    for (int mt = 0; mt < 2; ++mt)
        #pragma unroll
        for (int nt = 0; nt < 4; ++nt) acc[mt][nt] = (f32x4){0.f,0.f,0.f,0.f};

    bf16x8 bw[4];
    #pragma unroll
    for (int nt = 0; nt < 4; ++nt) bw[nt] = *(const bf16x8*)(tb + nt*4096);

    for (int kc = 0; kc < 8; ++kc) {
        int nk = (kc + 1 < 8) ? kc + 1 : 7;
        bf16x8 bn[4];
        #pragma unroll
        for (int nt = 0; nt < 4; ++nt) bn[nt] = *(const bf16x8*)(tb + nt*4096 + nk*32);
        bf16x8 af[2];
        #pragma unroll
        for (int mt = 0; mt < 2; ++mt)
            af[mt] = *(const bf16x8*)&As[(mt*16 + lm)*264 + kc*32 + lq*8];
        #pragma unroll
        for (int mt = 0; mt < 2; ++mt)
            #pragma unroll
            for (int nt = 0; nt < 4; ++nt)
                acc[mt][nt] = __builtin_amdgcn_mfma_f32_16x16x32_bf16(af[mt], bw[nt], acc[mt][nt], 0,0,0);
        #pragma unroll
        for (int nt = 0; nt < 4; ++nt) bw[nt] = bn[nt];
    }

    #pragma unroll
    for (int mt = 0; mt < 2; ++mt) {
        #pragma unroll
        for (int nt = 0; nt < 4; ++nt) {
            int n = w*64 + nt*16 + lm;
            float bb = Bi[n];
            #pragma unroll
            for (int j = 0; j < 4; ++j) {
                int m = m0 + mt*16 + lq*4 + j;
                U[(size_t)m*256 + n] = f2bf((acc[mt][nt][j] + bb) * sc);
            }
        }
    }
}

// ---------------------------------------------------------------- MFMA flash attention, inline V-T
// grid (128 = bp*8+h, 4 = kvb), 256 thr. V transposed into LDS once per block
// (replaces the vtrans kernel; same bf16 values, same fragment mapping).
__global__ __launch_bounds__(256) void attn_mfma2(
    const ushort* __restrict__ qab, const ushort* __restrict__ kab,
    const ushort* __restrict__ vab, const int* __restrict__ Rix,
    float* __restrict__ pl, float* __restrict__ pacc)
{
    __shared__ ushort P[4][16*40];
    __shared__ ushort Vs[32*200];     // [dk][key], stride 200
    int tid = threadIdx.x, w = tid >> 6, lane = tid & 63;
    int lm = lane & 15, lq = lane >> 4;
    int bph = blockIdx.x, kvb = blockIdx.y;
    int bp = bph >> 3, h = bph & 7, b = bp >> 3;
    int r = Rix[bp*4 + kvb];
    int vrow0 = (b*8 + r)*192;

    // stage V transposed: 1536 ushort4 chunks
    #pragma unroll
    for (int i = 0; i < 6; ++i) {
        int idx = i*256 + tid;
        int pos = idx >> 3, c4 = (idx & 7)*4;
        ushort4 v = *(const ushort4*)(vab + ((size_t)(vrow0 + pos))*256 + h*32 + c4);
        Vs[(c4+0)*200 + pos] = v.x;
        Vs[(c4+1)*200 + pos] = v.y;
        Vs[(c4+2)*200 + pos] = v.z;
        Vs[(c4+3)*200 + pos] = v.w;
    }

    bf16x8 qf[3];
    #pragma unroll
    for (int t = 0; t < 3; ++t)
        qf[t] = *(const bf16x8*)(qab + ((size_t)(bp*192 + w*48 + t*16 + lm))*256 + h*32 + lq*8);

    const ushort* kbase = kab + ((size_t)(vrow0))*256 + h*32 + lq*8;
    ushort* pw = P[w];
    __syncthreads();

    f32x4 O[3][2];
    #pragma unroll
    for (int t = 0; t < 3; ++t) { O[t][0] = (f32x4){0,0,0,0}; O[t][1] = (f32x4){0,0,0,0}; }
    float l[3] = {0.f, 0.f, 0.f};

    for (int k0 = 0; k0 < 192; k0 += 32) {
        bf16x8 kf0 = *(const bf16x8*)(kbase + (size_t)(k0 + lm)*256);
        bf16x8 kf1 = *(const bf16x8*)(kbase + (size_t)(k0 + 16 + lm)*256);
        bf16x8 vf0 = *(const bf16x8*)(&Vs[lm*200 + k0 + lq*8]);         // dk 0..15
        bf16x8 vf1 = *(const bf16x8*)(&Vs[(16 + lm)*200 + k0 + lq*8]);  // dk 16..31
        #pragma unroll
        for (int t = 0; t < 3; ++t) {
            f32x4 s0 = __builtin_amdgcn_mfma_f32_16x16x32_bf16(kf0, qf[t], (f32x4){0,0,0,0}, 0,0,0);
            f32x4 s1 = __builtin_amdgcn_mfma_f32_16x16x32_bf16(kf1, qf[t], (f32x4){0,0,0,0}, 0,0,0);
            float p0[4], p1[4];
            #pragma unroll
            for (int j = 0; j < 4; ++j) { p0[j] = __expf(s0[j]); p1[j] = __expf(s1[j]); }
            l[t] += p0[0]+p0[1]+p0[2]+p0[3] + p1[0]+p1[1]+p1[2]+p1[3];
            ushort4 a, c;
            a.x = f2bf(p0[0]); a.y = f2bf(p0[1]); a.z = f2bf(p0[2]); a.w = f2bf(p0[3]);
            c.x = f2bf(p1[0]); c.y = f2bf(p1[1]); c.z = f2bf(p1[2]); c.w = f2bf(p1[3]);
            *(ushort4*)(pw + lm*40 + lq*4)      = a;
            *(ushort4*)(pw + lm*40 + 16 + lq*4) = c;
            bf16x8 pf = *(const bf16x8*)(pw + lm*40 + lq*8);
            O[t][0] = __builtin_amdgcn_mfma_f32_16x16x32_bf16(pf, vf0, O[t][0], 0,0,0);
            O[t][1] = __builtin_amdgcn_mfma_f32_16x16x32_bf16(pf, vf1, O[t][1], 0,0,0);
        }
    }

    #pragma unroll
    for (int t = 0; t < 3; ++t) {
        float lt = l[t];
        lt += __shfl_xor(lt, 16);
        lt += __shfl_xor(lt, 32);
        size_t pbase = ((size_t)(bph*4 + kvb))*192 + w*48 + t*16;
        if (lq == 0) pl[pbase + lm] = lt;
        #pragma unroll
        for (int nt = 0; nt < 2; ++nt)
            #pragma unroll
            for (int reg = 0; reg < 4; ++reg)
                pacc[(pbase + lq*4 + reg)*32 + nt*16 + lm] = O[t][nt][reg];
    }
}

// ---------------------------------------------------------------- wo projection, fused merge + LN1
// Stage: ctx = (sum_k pacc)/(sum_k pl) -> bf16 (identical to old attn_merge2).
// GEMM: ctx @ woT + boa. Epilogue: +x, LayerNorm per row (identical to old ln_add).
__global__ __launch_bounds__(256) void gemm_wo_ln(
    const float* __restrict__ pl, const float* __restrict__ pacc,
    const ushort* __restrict__ T, const float* __restrict__ boa,
    const float* __restrict__ x,
    const float* __restrict__ g1, const float* __restrict__ b1,
    float* __restrict__ x_res)
{
    __shared__ __align__(16) ushort As[32*264];
    __shared__ float L2x[32*256];
    int tid = threadIdx.x;
    int m0 = blockIdx.x*32;
    // stage + merge
    #pragma unroll
    for (int i = 0; i < 4; ++i) {
        int c = i*256 + tid;
        int pos = c >> 5, off = (c & 31)*8;
        int m = m0 + pos;
        int bp = m / 192, q = m - bp*192;
        int h = off >> 5, d0 = off & 31;
        int bph = bp*8 + h;
        float ls = 0.f;
        float cv[8] = {0,0,0,0,0,0,0,0};
        #pragma unroll
        for (int k = 0; k < 4; ++k) {
            size_t pidx = ((size_t)(bph*4 + k))*192 + q;
            ls += pl[pidx];
            float4 a0 = *(const float4*)(pacc + pidx*32 + d0);
            float4 a1 = *(const float4*)(pacc + pidx*32 + d0 + 4);
            cv[0] += a0.x; cv[1] += a0.y; cv[2] += a0.z; cv[3] += a0.w;
            cv[4] += a1.x; cv[5] += a1.y; cv[6] += a1.z; cv[7] += a1.w;
        }
        ushort o[8];
        #pragma unroll
        for (int j = 0; j < 8; ++j) o[j] = f2bf(cv[j] / ls);
        *(ushort4*)&As[pos*264 + off]     = make_ushort4(o[0],o[1],o[2],o[3]);
        *(ushort4*)&As[pos*264 + off + 4] = make_ushort4(o[4],o[5],o[6],o[7]);
    }
    __syncthreads();
    int w = tid >> 6, lane = tid & 63, lm = lane & 15, lq = lane >> 4;
    const ushort* tb = T + ((size_t)(w*64 + lm))*256 + lq*8;

    f32x4 acc[2][4];
    #pragma unroll
    for (int mt = 0; mt < 2; ++mt)
        #pragma unroll
        for (int nt = 0; nt < 4; ++nt) acc[mt][nt] = (f32x4){0.f,0.f,0.f,0.f};

    bf16x8 bw[4];
    #pragma unroll
    for (int nt = 0; nt < 4; ++nt) bw[nt] = *(const bf16x8*)(tb + nt*4096);

    for (int kc = 0; kc < 8; ++kc) {
        int nk = (kc + 1 < 8) ? kc + 1 : 7;
        bf16x8 bn[4];
        #pragma unroll
        for (int nt = 0; nt < 4; ++nt) bn[nt] = *(const bf16x8*)(tb + nt*4096 + nk*32);
        bf16x8 af[2];
        #pragma unroll
        for (int mt = 0; mt < 2; ++mt)
            af[mt] = *(const bf16x8*)&As[(mt*16 + lm)*264 + kc*32 + lq*8];
        #pragma unroll
        for (int mt = 0; mt < 2; ++mt)
            #pragma unroll
            for (int nt = 0; nt < 4; ++nt)
                acc[mt][nt] = __builtin_amdgcn_mfma_f32_16x16x32_bf16(af[mt], bw[nt], acc[mt][nt], 0,0,0);
        #pragma unroll
        for (int nt = 0; nt < 4; ++nt) bw[nt] = bn[nt];
    }

    // epilogue: routing + x into LDS
    #pragma unroll
    for (int mt = 0; mt < 2; ++mt) {
        #pragma unroll
        for (int nt = 0; nt < 4; ++nt) {
            int n = w*64 + nt*16 + lm;
            float bb = boa[n];
            #pragma unroll
            for (int j = 0; j < 4; ++j) {
                int pos = mt*16 + lq*4 + j;
                float val = acc[mt][nt][j] + bb;
                L2x[pos*256 + n] = val + x[(size_t)(m0 + pos)*256 + n];
            }
        }
    }
    __syncthreads();
    // LayerNorm rows (same lane grouping + shuffle tree as old ln_add)
    #pragma unroll
    for (int rr = 0; rr < 8; ++rr) {
        int pos = w*8 + rr;
        float4 a = *(const float4*)(&L2x[pos*256 + lane*4]);
        float x0 = a.x, x1 = a.y, x2 = a.z, x3 = a.w;
        float s  = x0 + x1 + x2 + x3;
        float sq = x0*x0 + x1*x1 + x2*x2 + x3*x3;
        #pragma unroll
        for (int off = 32; off > 0; off >>= 1) {
            s  += __shfl_xor(s,  off);
            sq += __shfl_xor(sq, off);
        }
        float mean = s * (1.0f/256.0f);
        float var  = sq * (1.0f/256.0f) - mean*mean;
        float rstd = rsqrtf(var + 1e-5f);
        float4 gv = *(const float4*)(g1 + lane*4);
        float4 bv = *(const float4*)(b1 + lane*4);
        float4 o;
        o.x = (x0 - mean)*rstd*gv.x + bv.x;
        o.y = (x1 - mean)*rstd*gv.y + bv.y;
        o.z = (x2 - mean)*rstd*gv.z + bv.z;
        o.w = (x3 - mean)*rstd*gv.w + bv.w;
        *(float4*)(x_res + (size_t)(m0 + pos)*256 + lane*4) = o;
    }
}

// ---------------------------------------------------------------- padded bf16 conv input (bf16 in)
__global__ __launch_bounds__(256) void addkv_pad2(
    const ushort* __restrict__ kpb, const ushort* __restrict__ vpb, ushort* __restrict__ kvb)
{
    int t  = blockIdx.x*256 + threadIdx.x;
    int ci = (t & 63) * 4;
    int p  = t >> 6;
    int xp = p % 28;
    int rr = p / 28;
    int yp = rr % 68;
    int b  = rr / 68;
    int y = yp - 2, x = xp - 2;
    ushort4 o; o.x = 0; o.y = 0; o.z = 0; o.w = 0;
    if (y >= 0 && y < 64 && x >= 0 && x < 24) {
        size_t base = ((size_t)((b*64 + y)*24 + x))*256 + ci;
        ushort4 a = *(const ushort4*)(kpb + base);
        ushort4 c = *(const ushort4*)(vpb + base);
        o.x = f2bf(bf2f(a.x) + bf2f(c.x));
        o.y = f2bf(bf2f(a.y) + bf2f(c.y));
        o.z = f2bf(bf2f(a.z) + bf2f(c.z));
        o.w = f2bf(bf2f(a.w) + bf2f(c.w));
    }
    *(ushort4*)(kvb + (size_t)p*256 + ci) = o;
}

// ---------------------------------------------------------------- implicit-GEMM conv v5
// Single image row per block: grid = 128 rows x 5 dy = 640 blocks (~2.5 blocks/CU
// resident -> 2.5 waves/SIMD TLP; round-7's 320-block grid gave 1.25, no latency
// hiding). Depth-2 B register prefetch kept. Normal stores (nt didn't help).
__global__ __launch_bounds__(256) void conv_mfma4(
    const ushort* __restrict__ kvb, const ushort* __restrict__ wct,
    float* __restrict__ pconv)
{
    __shared__ __align__(16) ushort Arow[9504];   // 36 pos x 264 (28 filled + overrun)
    int tid = threadIdx.x;
    int bid = blockIdx.x;                 // row*5 + dy
    int row = bid / 5, dy = bid - row*5;
    int b = row >> 6, y = row & 63;

    const ushort* src = kvb + ((size_t)((b*68 + y + dy)*28))*256;
    #pragma unroll
    for (int i = 0; i < 4; ++i) {
        int c = i*256 + tid;              // 1024 slots, 896 used
        if (c < 896) {
            int pos = c >> 5, off = (c & 31)*8;
            *(bf16x8*)(&Arow[pos*264 + off]) = *(const bf16x8*)(src + (size_t)(pos*256 + off));
        }
    }
    __syncthreads();

    int w = tid >> 6;
    int lane = tid & 63, lm = lane & 15, lq = lane >> 4;
    const ushort* bbase = wct + ((size_t)((dy*5)*256 + w*64 + lm))*256 + lq*8;
    const ushort* a00 = &Arow[lm*264 + lq*8];

    f32x4 acc[2][4];
    #pragma unroll
    for (int mt = 0; mt < 2; ++mt)
        #pragma unroll
        for (int nt = 0; nt < 4; ++nt)
            acc[mt][nt] = (f32x4){0.f,0.f,0.f,0.f};

    bf16x8 b0[4], b1[4];
    #pragma unroll
    for (int nt = 0; nt < 4; ++nt) b0[nt] = *(const bf16x8*)(bbase + nt*4096);
    #pragma unroll
    for (int nt = 0; nt < 4; ++nt) b1[nt] = *(const bf16x8*)(bbase + 32 + nt*4096);

    for (int iter = 0; iter < 40; ++iter) {          // iter = dx*8 + ch
        int i2 = (iter + 2 < 40) ? iter + 2 : 39;
        int boff = (i2 >> 3)*65536 + (i2 & 7)*32;
        bf16x8 bn[4];
        #pragma unroll
        for (int nt = 0; nt < 4; ++nt) bn[nt] = *(const bf16x8*)(bbase + boff + nt*4096);

        int aoff = (iter >> 3)*264 + (iter & 7)*32;  // dx*264 + ch*32
        bf16x8 af[2];
        #pragma unroll
        for (int mt = 0; mt < 2; ++mt)
            af[mt] = *(const bf16x8*)(a00 + mt*4224 + aoff);

        #pragma unroll
        for (int mt = 0; mt < 2; ++mt)
            #pragma unroll
            for (int nt = 0; nt < 4; ++nt)
                acc[mt][nt] = __builtin_amdgcn_mfma_f32_16x16x32_bf16(
                    af[mt], b0[nt], acc[mt][nt], 0, 0, 0);

        #pragma unroll
        for (int nt = 0; nt < 4; ++nt) { b0[nt] = b1[nt]; b1[nt] = bn[nt]; }
    }

    #pragma unroll
    for (int mt = 0; mt < 2; ++mt) {
        #pragma unroll
        for (int nt = 0; nt < 4; ++nt) {
            #pragma unroll
            for (int j = 0; j < 4; ++j) {
                int x = mt*16 + lq*4 + j;
                if (x < 24)
                    pconv[((size_t)(dy*3072 + row*24 + x))*256 + w*64 + nt*16 + lm]
                        = acc[mt][nt][j];
            }
        }
    }
}

// ---------------------------------------------------------------- LN2 fused with dy-reduce
__global__ __launch_bounds__(256) void ln2_fused(
    const float* __restrict__ xr, const float* __restrict__ pc, const float* __restrict__ cb,
    const float* __restrict__ gamma, const float* __restrict__ beta,
    float* __restrict__ out)
{
    int pos  = blockIdx.x*4 + (threadIdx.x >> 6);
    int lane = threadIdx.x & 63;
    size_t base = (size_t)pos*256 + lane*4;
    float4 gsum = *(const float4*)(cb + lane*4);
    #pragma unroll
    for (int d = 0; d < 5; ++d) {
        float4 v = *(const float4*)(pc + (size_t)d*NE + base);
        gsum.x += v.x; gsum.y += v.y; gsum.z += v.z; gsum.w += v.w;
    }
    float4 a = *(const float4*)(xr + base);
    float x0 = a.x + gsum.x, x1 = a.y + gsum.y, x2 = a.z + gsum.z, x3 = a.w + gsum.w;
    float s  = x0 + x1 + x2 + x3;
    float sq = x0*x0 + x1*x1 + x2*x2 + x3*x3;
    #pragma unroll
    for (int off = 32; off > 0; off >>= 1) {
        s  += __shfl_xor(s,  off);
        sq += __shfl_xor(sq, off);
    }
    float mean = s * (1.0f/256.0f);
    float var  = sq * (1.0f/256.0f) - mean*mean;
    float rstd = rsqrtf(var + 1e-5f);
    float4 gv = *(const float4*)(gamma + lane*4);
    float4 bv = *(const float4*)(beta  + lane*4);
    float4 o;
    o.x = (x0 - mean)*rstd*gv.x + bv.x;
    o.y = (x1 - mean)*rstd*gv.y + bv.y;
    o.z = (x2 - mean)*rstd*gv.z + bv.z;
    o.w = (x3 - mean)*rstd*gv.w + bv.w;
    *(float4*)(out + base) = o;
}

// ---------------------------------------------------------------- launcher
extern "C" void kernel_launch(void* const* d_in, const int* in_sizes, int n_in,
                              void* d_out, int out_size, void* d_ws, size_t ws_size,
                              hipStream_t stream)
{
    (void)in_sizes; (void)n_in; (void)out_size; (void)ws_size;
    const float* x    = (const float*)d_in[0];
    const float* wq   = (const float*)d_in[1];
    const float* bq   = (const float*)d_in[2];
    const float* wk   = (const float*)d_in[3];
    const float* bk   = (const float*)d_in[4];
    const float* wv   = (const float*)d_in[5];
    const float* bv   = (const float*)d_in[6];
    const float* wqa  = (const float*)d_in[7];
    const float* bqa  = (const float*)d_in[8];
    const float* wka  = (const float*)d_in[9];
    const float* bka  = (const float*)d_in[10];
    const float* wva  = (const float*)d_in[11];
    const float* bva  = (const float*)d_in[12];
    const float* woa  = (const float*)d_in[13];
    const float* boa  = (const float*)d_in[14];
    const float* cw   = (const float*)d_in[15];
    const float* cbi  = (const float*)d_in[16];
    const float* ln1g = (const float*)d_in[17];
    const float* ln1b = (const float*)d_in[18];
    const float* ln2g = (const float*)d_in[19];
    const float* ln2b = (const float*)d_in[20];
    float* out = (float*)d_out;

    float* ws = (float*)d_ws;
    const size_t HNE = NE/2;
    ushort* qpb = (ushort*)(ws + 0*HNE);
    ushort* kpb = (ushort*)(ws + 1*HNE);
    ushort* xb  = (ushort*)(ws + 2*HNE);   // slot used as x_res (fp32)
    ushort* vpb = (ushort*)(ws + 3*HNE);
    ushort* qab = (ushort*)(ws + 4*HNE);
    ushort* kab = (ushort*)(ws + 5*HNE);
    ushort* vab = (ushort*)(ws + 6*HNE);
    // slot 7 (old vt) now unused
    float* R    = ws + 8*HNE;              // 3,932,160 floats
    float* pacc = R;
    float* pl   = R + 3145728;
    float* pconv= R;                       // reuses R after gemm_wo_ln consumed pacc/pl
    ushort* wt7 = (ushort*)(R + 3932160);
    ushort* wct = (ushort*)(R + 3932160 + 229376);
    ushort* kvb = (ushort*)(R + 3932160 + 229376 + 819200);
    float* qloc = R + 3932160 + 229376 + 819200 + 487424;
    float* kloc = qloc + 4096;
    int*   Rix  = (int*)(kloc + 4096);
    float* x_res = (float*)xb;             // xb+vpb slots: fp32 NE after both dead

    // 1. weight preps
    wtrans7<<<dim3(16,7), 256, 0, stream>>>(wq,wk,wv,wqa,wka,wva,woa, wt7);
    wtrans<<<400, 256, 0, stream>>>(cw, wct);
    // 2. routing (fused mean+projection, fp32 exact) + top-k
    qkloc2<<<dim3(16,2), 256, 0, stream>>>(x, wq,bq, wk,bk, qloc, kloc);
    topk_kern<<<2, 64, 0, stream>>>(qloc, kloc, Rix);
    // 3. q/k/v projections (bf16 MFMA)
    gemm_btx3<<<dim3(96,3), 256, 0, stream>>>(
        x, wt7, wt7+65536, wt7+131072, bq,bk,bv, qpb,kpb,vpb);
    // 4. conv input (bf16)
    addkv_pad2<<<952, 256, 0, stream>>>(kpb, vpb, kvb);
    // 5. attention projections (qab pre-scaled by 1/sqrt(dk))
    gemm_bt3<<<dim3(96,3), 256, 0, stream>>>(
        qpb,kpb,vpb, wt7+196608, wt7+262144, wt7+327680, bqa,bka,bva,
        qab,kab,vab, 0.17677669529663687f,1.f,1.f);
    // 6. MFMA flash attention (inline V-transpose)
    attn_mfma2<<<dim3(128,4), 256, 0, stream>>>(qab, kab, vab, Rix, pl, pacc);
    // 7. wo projection fused with merge + LN1 -> x_res
    gemm_wo_ln<<<96, 256, 0, stream>>>(pl, pacc, wt7+393216, boa, x, ln1g, ln1b, x_res);
    // 8. conv v5 (640-block TLP grid)
    conv_mfma4<<<640, 256, 0, stream>>>(kvb, wct, pconv);
    // 9. LN2 fused with dy-reduce + bias -> out
    ln2_fused<<<NPOS/4, 256, 0, stream>>>(x_res, pconv, cbi, ln2g, ln2b, out);
}

// Round 9
// 212.084 us; speedup vs baseline: 1.1087x; 1.1087x over previous
//
#include <hip/hip_runtime.h>
#include <hip/hip_bf16.h>

// DRSA temporal block. B=2, P=8, hp=8, W=24, C=256, NH=8, dk=32, kv=4, H=64.
// 3072 positions, [pos][256] row-major. All GEMM-shaped work on bf16 MFMA.
// 11 dispatches. Conv v6: block=(row-pair, dy, co-half), wave=co-eighth ->
// 16 MFMA per 2 B-frags (round-7 reuse ratio) AND 640 blocks (round-8 TLP).

#define NPOS 3072
#define CD   256
#define NE   (NPOS*CD)

typedef short bf16x8 __attribute__((ext_vector_type(8)));
typedef float f32x4  __attribute__((ext_vector_type(4)));

__device__ inline ushort f2bf(float f) {
    __hip_bfloat16 h = __float2bfloat16(f);   // RNE
    return *reinterpret_cast<ushort*>(&h);
}
__device__ inline float bf2f(ushort u) {
    unsigned v = ((unsigned)u) << 16;
    return *reinterpret_cast<float*>(&v);
}

// ---------------------------------------------------------------- 7 weight transposes -> bf16
__global__ __launch_bounds__(256) void wtrans7(
    const float* __restrict__ w0, const float* __restrict__ w1, const float* __restrict__ w2,
    const float* __restrict__ w3, const float* __restrict__ w4, const float* __restrict__ w5,
    const float* __restrict__ w6, ushort* __restrict__ wt)
{
    __shared__ float l[64*65];
    int mat = blockIdx.y;
    const float* Wm = mat==0?w0:mat==1?w1:mat==2?w2:mat==3?w3:mat==4?w4:mat==5?w5:w6;
    int r2 = blockIdx.x;
    int ci0 = (r2 >> 2)*64, co0 = (r2 & 3)*64;
    int tid = threadIdx.x, a = tid >> 6, c = tid & 63;
    #pragma unroll 4
    for (int k = 0; k < 16; ++k) {
        int cil = k*4 + a;
        l[cil*65 + c] = Wm[(size_t)(ci0 + cil)*256 + co0 + c];
    }
    __syncthreads();
    #pragma unroll 4
    for (int k = 0; k < 16; ++k) {
        int col = k*4 + a;
        wt[(size_t)mat*65536 + ((size_t)(co0 + col))*256 + ci0 + c] = f2bf(l[c*65 + col]);
    }
}

// ---------------------------------------------------------------- conv weight transpose
__global__ __launch_bounds__(256) void wtrans(
    const float* __restrict__ cw, ushort* __restrict__ wct)
{
    __shared__ float l[64*65];
    int blk = blockIdx.x;
    int tap = blk >> 4;
    int r2  = blk & 15;
    int ci0 = (r2 >> 2) * 64;
    int co0 = (r2 & 3) * 64;
    int tid = threadIdx.x;
    int a = tid >> 6;
    int c = tid & 63;
    #pragma unroll 4
    for (int k = 0; k < 16; ++k) {
        int cil = k*4 + a;
        l[cil*65 + c] = cw[(size_t)tap*65536 + (size_t)(ci0 + cil)*256 + co0 + c];
    }
    __syncthreads();
    #pragma unroll 4
    for (int k = 0; k < 16; ++k) {
        int col = k*4 + a;
        wct[((size_t)(tap*256 + co0 + col))*256 + ci0 + c] = f2bf(l[c*65 + col]);
    }
}

// ---------------------------------------------------------------- fused xmean + q/k_loc [fp32 exact]
__global__ __launch_bounds__(256) void qkloc2(
    const float* __restrict__ x,
    const float* __restrict__ wq, const float* __restrict__ bq,
    const float* __restrict__ wk, const float* __restrict__ bk,
    float* __restrict__ qloc, float* __restrict__ kloc)
{
    __shared__ float xs[256];
    int bp = blockIdx.x, c = threadIdx.x;
    float s = 0.f;
    for (int i = 0; i < 192; ++i)
        s += x[((size_t)(bp*192 + i))*256 + c];
    xs[c] = s * (1.0f/192.0f);
    __syncthreads();
    const float* W  = blockIdx.y ? wk : wq;
    const float* Bv = blockIdx.y ? bk : bq;
    float* dst      = blockIdx.y ? kloc : qloc;
    float acc = Bv[c];
    #pragma unroll 8
    for (int k = 0; k < 256; ++k)
        acc += xs[k] * W[(size_t)k*256 + c];
    dst[bp*256 + c] = acc;
}

// ---------------------------------------------------------------- routing top-k (fp32 exact)
__global__ void topk_kern(const float* __restrict__ qloc, const float* __restrict__ kloc,
                          int* __restrict__ Rix)
{
    __shared__ float S[64];
    int b = blockIdx.x, t = threadIdx.x;
    int p = t >> 3, qq = t & 7;
    float s = 0.f;
    for (int c = 0; c < 256; ++c)
        s += qloc[(b*8+p)*256 + c] * kloc[(b*8+qq)*256 + c];
    S[t] = s;
    __syncthreads();
    if (t < 8) {
        float vals[8];
        #pragma unroll
        for (int j = 0; j < 8; ++j) vals[j] = S[t*8 + j];
        for (int j = 0; j < 4; ++j) {
            int best = 0; float bv = vals[0];
            #pragma unroll
            for (int i = 1; i < 8; ++i) if (vals[i] > bv) { bv = vals[i]; best = i; }
            Rix[(b*8 + t)*4 + j] = best;
            vals[best] = -1e30f;
        }
    }
}

// ---------------------------------------------------------------- bf16 MFMA GEMM triple, fp32 A
__global__ __launch_bounds__(256) void gemm_btx3(
    const float* __restrict__ A,
    const ushort* __restrict__ T0, const ushort* __restrict__ T1, const ushort* __restrict__ T2,
    const float* __restrict__ B0, const float* __restrict__ B1, const float* __restrict__ B2,
    ushort* __restrict__ U0, ushort* __restrict__ U1, ushort* __restrict__ U2)
{
    __shared__ __align__(16) ushort As[32*264];
    int y = blockIdx.y;
    const ushort* T = y==0 ? T0 : (y==1 ? T1 : T2);
    const float* Bi = y==0 ? B0 : (y==1 ? B1 : B2);
    ushort* U = y==0 ? U0 : (y==1 ? U1 : U2);
    int tid = threadIdx.x;
    int m0 = blockIdx.x*32;
    #pragma unroll
    for (int i = 0; i < 4; ++i) {
        int c = i*256 + tid;
        int pos = c >> 5, off = (c & 31)*8;
        const float* src = A + (size_t)(m0 + pos)*256 + off;
        float4 v0 = *(const float4*)src;
        float4 v1 = *(const float4*)(src + 4);
        ushort4 o0, o1;
        o0.x = f2bf(v0.x); o0.y = f2bf(v0.y); o0.z = f2bf(v0.z); o0.w = f2bf(v0.w);
        o1.x = f2bf(v1.x); o1.y = f2bf(v1.y); o1.z = f2bf(v1.z); o1.w = f2bf(v1.w);
        *(ushort4*)&As[pos*264 + off]     = o0;
        *(ushort4*)&As[pos*264 + off + 4] = o1;
    }
    __syncthreads();
    int w = tid >> 6, lane = tid & 63, lm = lane & 15, lq = lane >> 4;
    const ushort* tb = T + ((size_t)(w*64 + lm))*256 + lq*8;

    f32x4 acc[2][4];
    #pragma unroll
    for (int mt = 0; mt < 2; ++mt)
        #pragma unroll
        for (int nt = 0; nt < 4; ++nt) acc[mt][nt] = (f32x4){0.f,0.f,0.f,0.f};

    bf16x8 bw[4];
    #pragma unroll
    for (int nt = 0; nt < 4; ++nt) bw[nt] = *(const bf16x8*)(tb + nt*4096);

    for (int kc = 0; kc < 8; ++kc) {
        int nk = (kc + 1 < 8) ? kc + 1 : 7;
        bf16x8 bn[4];
        #pragma unroll
        for (int nt = 0; nt < 4; ++nt) bn[nt] = *(const bf16x8*)(tb + nt*4096 + nk*32);
        bf16x8 af[2];
        #pragma unroll
        for (int mt = 0; mt < 2; ++mt)
            af[mt] = *(const bf16x8*)&As[(mt*16 + lm)*264 + kc*32 + lq*8];
        #pragma unroll
        for (int mt = 0; mt < 2; ++mt)
            #pragma unroll
            for (int nt = 0; nt < 4; ++nt)
                acc[mt][nt] = __builtin_amdgcn_mfma_f32_16x16x32_bf16(af[mt], bw[nt], acc[mt][nt], 0,0,0);
        #pragma unroll
        for (int nt = 0; nt < 4; ++nt) bw[nt] = bn[nt];
    }

    #pragma unroll
    for (int mt = 0; mt < 2; ++mt) {
        #pragma unroll
        for (int nt = 0; nt < 4; ++nt) {
            int n = w*64 + nt*16 + lm;
            float bb = Bi[n];
            #pragma unroll
            for (int j = 0; j < 4; ++j) {
                int m = m0 + mt*16 + lq*4 + j;
                U[(size_t)m*256 + n] = f2bf(acc[mt][nt][j] + bb);
            }
        }
    }
}

// ---------------------------------------------------------------- bf16 MFMA GEMM triple, bf16 A
__global__ __launch_bounds__(256) void gemm_bt3(
    const ushort* __restrict__ A0, const ushort* __restrict__ A1, const ushort* __restrict__ A2,
    const ushort* __restrict__ T0, const ushort* __restrict__ T1, const ushort* __restrict__ T2,
    const float* __restrict__ B0, const float* __restrict__ B1, const float* __restrict__ B2,
    ushort* __restrict__ U0, ushort* __restrict__ U1, ushort* __restrict__ U2,
    float s0, float s1, float s2)
{
    __shared__ __align__(16) ushort As[32*264];
    int y = blockIdx.y;
    const ushort* A = y==0 ? A0 : (y==1 ? A1 : A2);
    const ushort* T = y==0 ? T0 : (y==1 ? T1 : T2);
    const float* Bi = y==0 ? B0 : (y==1 ? B1 : B2);
    ushort* U = y==0 ? U0 : (y==1 ? U1 : U2);
    float  sc = y==0 ? s0 : (y==1 ? s1 : s2);
    int tid = threadIdx.x;
    int m0 = blockIdx.x*32;
    #pragma unroll
    for (int i = 0; i < 4; ++i) {
        int c = i*256 + tid;
        int pos = c >> 5, off = (c & 31)*8;
        *(bf16x8*)&As[pos*264 + off] = *(const bf16x8*)(A + (size_t)(m0 + pos)*256 + off);
    }
    __syncthreads();
    int w = tid >> 6, lane = tid & 63, lm = lane & 15, lq = lane >> 4;
    const ushort* tb = T + ((size_t)(w*64 + lm))*256 + lq*8;

    f32x4 acc[2][4];
    #pragma unroll
    for (int mt = 0; mt < 2; ++mt)
        #pragma unroll
        for (int nt = 0; nt < 4; ++nt) acc[mt][nt] = (f32x4){0.f,0.f,0.f,0.f};

    bf16x8 bw[4];
    #pragma unroll
    for (int nt = 0; nt < 4; ++nt) bw[nt] = *(const bf16x8*)(tb + nt*4096);

    for (int kc = 0; kc < 8; ++kc) {
        int nk = (kc + 1 < 8) ? kc + 1 : 7;
        bf16x8 bn[4];
        #pragma unroll
        for (int nt = 0; nt < 4; ++nt) bn[nt] = *(const bf16x8*)(tb + nt*4096 + nk*32);
        bf16x8 af[2];
        #pragma unroll
        for (int mt = 0; mt < 2; ++mt)
            af[mt] = *(const bf16x8*)&As[(mt*16 + lm)*264 + kc*32 + lq*8];
        #pragma unroll
        for (int mt = 0; mt < 2; ++mt)
            #pragma unroll
            for (int nt = 0; nt < 4; ++nt)
                acc[mt][nt] = __builtin_amdgcn_mfma_f32_16x16x32_bf16(af[mt], bw[nt], acc[mt][nt], 0,0,0);
        #pragma unroll
        for (int nt = 0; nt < 4; ++nt) bw[nt] = bn[nt];
    }

    #pragma unroll
    for (int mt = 0; mt < 2; ++mt) {
        #pragma unroll
        for (int nt = 0; nt < 4; ++nt) {
            int n = w*64 + nt*16 + lm;
            float bb = Bi[n];
            #pragma unroll
            for (int j = 0; j < 4; ++j) {
                int m = m0 + mt*16 + lq*4 + j;
                U[(size_t)m*256 + n] = f2bf((acc[mt][nt][j] + bb) * sc);
            }
        }
    }
}

// ---------------------------------------------------------------- MFMA flash attention, inline V-T
__global__ __launch_bounds__(256) void attn_mfma2(
    const ushort* __restrict__ qab, const ushort* __restrict__ kab,
    const ushort* __restrict__ vab, const int* __restrict__ Rix,
    float* __restrict__ pl, float* __restrict__ pacc)
{
    __shared__ ushort P[4][16*40];
    __shared__ ushort Vs[32*200];     // [dk][key], stride 200
    int tid = threadIdx.x, w = tid >> 6, lane = tid & 63;
    int lm = lane & 15, lq = lane >> 4;
    int bph = blockIdx.x, kvb = blockIdx.y;
    int bp = bph >> 3, h = bph & 7, b = bp >> 3;
    int r = Rix[bp*4 + kvb];
    int vrow0 = (b*8 + r)*192;

    #pragma unroll
    for (int i = 0; i < 6; ++i) {
        int idx = i*256 + tid;
        int pos = idx >> 3, c4 = (idx & 7)*4;
        ushort4 v = *(const ushort4*)(vab + ((size_t)(vrow0 + pos))*256 + h*32 + c4);
        Vs[(c4+0)*200 + pos] = v.x;
        Vs[(c4+1)*200 + pos] = v.y;
        Vs[(c4+2)*200 + pos] = v.z;
        Vs[(c4+3)*200 + pos] = v.w;
    }

    bf16x8 qf[3];
    #pragma unroll
    for (int t = 0; t < 3; ++t)
        qf[t] = *(const bf16x8*)(qab + ((size_t)(bp*192 + w*48 + t*16 + lm))*256 + h*32 + lq*8);

    const ushort* kbase = kab + ((size_t)(vrow0))*256 + h*32 + lq*8;
    ushort* pw = P[w];
    __syncthreads();

    f32x4 O[3][2];
    #pragma unroll
    for (int t = 0; t < 3; ++t) { O[t][0] = (f32x4){0,0,0,0}; O[t][1] = (f32x4){0,0,0,0}; }
    float l[3] = {0.f, 0.f, 0.f};

    for (int k0 = 0; k0 < 192; k0 += 32) {
        bf16x8 kf0 = *(const bf16x8*)(kbase + (size_t)(k0 + lm)*256);
        bf16x8 kf1 = *(const bf16x8*)(kbase + (size_t)(k0 + 16 + lm)*256);
        bf16x8 vf0 = *(const bf16x8*)(&Vs[lm*200 + k0 + lq*8]);
        bf16x8 vf1 = *(const bf16x8*)(&Vs[(16 + lm)*200 + k0 + lq*8]);
        #pragma unroll
        for (int t = 0; t < 3; ++t) {
            f32x4 s0 = __builtin_amdgcn_mfma_f32_16x16x32_bf16(kf0, qf[t], (f32x4){0,0,0,0}, 0,0,0);
            f32x4 s1 = __builtin_amdgcn_mfma_f32_16x16x32_bf16(kf1, qf[t], (f32x4){0,0,0,0}, 0,0,0);
            float p0[4], p1[4];
            #pragma unroll
            for (int j = 0; j < 4; ++j) { p0[j] = __expf(s0[j]); p1[j] = __expf(s1[j]); }
            l[t] += p0[0]+p0[1]+p0[2]+p0[3] + p1[0]+p1[1]+p1[2]+p1[3];
            ushort4 a, c;
            a.x = f2bf(p0[0]); a.y = f2bf(p0[1]); a.z = f2bf(p0[2]); a.w = f2bf(p0[3]);
            c.x = f2bf(p1[0]); c.y = f2bf(p1[1]); c.z = f2bf(p1[2]); c.w = f2bf(p1[3]);
            *(ushort4*)(pw + lm*40 + lq*4)      = a;
            *(ushort4*)(pw + lm*40 + 16 + lq*4) = c;
            bf16x8 pf = *(const bf16x8*)(pw + lm*40 + lq*8);
            O[t][0] = __builtin_amdgcn_mfma_f32_16x16x32_bf16(pf, vf0, O[t][0], 0,0,0);
            O[t][1] = __builtin_amdgcn_mfma_f32_16x16x32_bf16(pf, vf1, O[t][1], 0,0,0);
        }
    }

    #pragma unroll
    for (int t = 0; t < 3; ++t) {
        float lt = l[t];
        lt += __shfl_xor(lt, 16);
        lt += __shfl_xor(lt, 32);
        size_t pbase = ((size_t)(bph*4 + kvb))*192 + w*48 + t*16;
        if (lq == 0) pl[pbase + lm] = lt;
        #pragma unroll
        for (int nt = 0; nt < 2; ++nt)
            #pragma unroll
            for (int reg = 0; reg < 4; ++reg)
                pacc[(pbase + lq*4 + reg)*32 + nt*16 + lm] = O[t][nt][reg];
    }
}

// ---------------------------------------------------------------- wo projection, fused merge + LN1
__global__ __launch_bounds__(256) void gemm_wo_ln(
    const float* __restrict__ pl, const float* __restrict__ pacc,
    const ushort* __restrict__ T, const float* __restrict__ boa,
    const float* __restrict__ x,
    const float* __restrict__ g1, const float* __restrict__ b1,
    float* __restrict__ x_res)
{
    __shared__ __align__(16) ushort As[32*264];
    __shared__ float L2x[32*256];
    int tid = threadIdx.x;
    int m0 = blockIdx.x*32;
    #pragma unroll
    for (int i = 0; i < 4; ++i) {
        int c = i*256 + tid;
        int pos = c >> 5, off = (c & 31)*8;
        int m = m0 + pos;
        int bp = m / 192, q = m - bp*192;
        int h = off >> 5, d0 = off & 31;
        int bph = bp*8 + h;
        float ls = 0.f;
        float cv[8] = {0,0,0,0,0,0,0,0};
        #pragma unroll
        for (int k = 0; k < 4; ++k) {
            size_t pidx = ((size_t)(bph*4 + k))*192 + q;
            ls += pl[pidx];
            float4 a0 = *(const float4*)(pacc + pidx*32 + d0);
            float4 a1 = *(const float4*)(pacc + pidx*32 + d0 + 4);
            cv[0] += a0.x; cv[1] += a0.y; cv[2] += a0.z; cv[3] += a0.w;
            cv[4] += a1.x; cv[5] += a1.y; cv[6] += a1.z; cv[7] += a1.w;
        }
        ushort o[8];
        #pragma unroll
        for (int j = 0; j < 8; ++j) o[j] = f2bf(cv[j] / ls);
        *(ushort4*)&As[pos*264 + off]     = make_ushort4(o[0],o[1],o[2],o[3]);
        *(ushort4*)&As[pos*264 + off + 4] = make_ushort4(o[4],o[5],o[6],o[7]);
    }
    __syncthreads();
    int w = tid >> 6, lane = tid & 63, lm = lane & 15, lq = lane >> 4;
    const ushort* tb = T + ((size_t)(w*64 + lm))*256 + lq*8;

    f32x4 acc[2][4];
    #pragma unroll
    for (int mt = 0; mt < 2; ++mt)
        #pragma unroll
        for (int nt = 0; nt < 4; ++nt) acc[mt][nt] = (f32x4){0.f,0.f,0.f,0.f};

    bf16x8 bw[4];
    #pragma unroll
    for (int nt = 0; nt < 4; ++nt) bw[nt] = *(const bf16x8*)(tb + nt*4096);

    for (int kc = 0; kc < 8; ++kc) {
        int nk = (kc + 1 < 8) ? kc + 1 : 7;
        bf16x8 bn[4];
        #pragma unroll
        for (int nt = 0; nt < 4; ++nt) bn[nt] = *(const bf16x8*)(tb + nt*4096 + nk*32);
        bf16x8 af[2];
        #pragma unroll
        for (int mt = 0; mt < 2; ++mt)
            af[mt] = *(const bf16x8*)&As[(mt*16 + lm)*264 + kc*32 + lq*8];
        #pragma unroll
        for (int mt = 0; mt < 2; ++mt)
            #pragma unroll
            for (int nt = 0; nt < 4; ++nt)
                acc[mt][nt] = __builtin_amdgcn_mfma_f32_16x16x32_bf16(af[mt], bw[nt], acc[mt][nt], 0,0,0);
        #pragma unroll
        for (int nt = 0; nt < 4; ++nt) bw[nt] = bn[nt];
    }

    #pragma unroll
    for (int mt = 0; mt < 2; ++mt) {
        #pragma unroll
        for (int nt = 0; nt < 4; ++nt) {
            int n = w*64 + nt*16 + lm;
            float bb = boa[n];
            #pragma unroll
            for (int j = 0; j < 4; ++j) {
                int pos = mt*16 + lq*4 + j;
                float val = acc[mt][nt][j] + bb;
                L2x[pos*256 + n] = val + x[(size_t)(m0 + pos)*256 + n];
            }
        }
    }
    __syncthreads();
    #pragma unroll
    for (int rr = 0; rr < 8; ++rr) {
        int pos = w*8 + rr;
        float4 a = *(const float4*)(&L2x[pos*256 + lane*4]);
        float x0 = a.x, x1 = a.y, x2 = a.z, x3 = a.w;
        float s  = x0 + x1 + x2 + x3;
        float sq = x0*x0 + x1*x1 + x2*x2 + x3*x3;
        #pragma unroll
        for (int off = 32; off > 0; off >>= 1) {
            s  += __shfl_xor(s,  off);
            sq += __shfl_xor(sq, off);
        }
        float mean = s * (1.0f/256.0f);
        float var  = sq * (1.0f/256.0f) - mean*mean;
        float rstd = rsqrtf(var + 1e-5f);
        float4 gv = *(const float4*)(g1 + lane*4);
        float4 bv = *(const float4*)(b1 + lane*4);
        float4 o;
        o.x = (x0 - mean)*rstd*gv.x + bv.x;
        o.y = (x1 - mean)*rstd*gv.y + bv.y;
        o.z = (x2 - mean)*rstd*gv.z + bv.z;
        o.w = (x3 - mean)*rstd*gv.w + bv.w;
        *(float4*)(x_res + (size_t)(m0 + pos)*256 + lane*4) = o;
    }
}

// ---------------------------------------------------------------- padded bf16 conv input (bf16 in)
__global__ __launch_bounds__(256) void addkv_pad2(
    const ushort* __restrict__ kpb, const ushort* __restrict__ vpb, ushort* __restrict__ kvb)
{
    int t  = blockIdx.x*256 + threadIdx.x;
    int ci = (t & 63) * 4;
    int p  = t >> 6;
    int xp = p % 28;
    int rr = p / 28;
    int yp = rr % 68;
    int b  = rr / 68;
    int y = yp - 2, x = xp - 2;
    ushort4 o; o.x = 0; o.y = 0; o.z = 0; o.w = 0;
    if (y >= 0 && y < 64 && x >= 0 && x < 24) {
        size_t base = ((size_t)((b*64 + y)*24 + x))*256 + ci;
        ushort4 a = *(const ushort4*)(kpb + base);
        ushort4 c = *(const ushort4*)(vpb + base);
        o.x = f2bf(bf2f(a.x) + bf2f(c.x));
        o.y = f2bf(bf2f(a.y) + bf2f(c.y));
        o.z = f2bf(bf2f(a.z) + bf2f(c.z));
        o.w = f2bf(bf2f(a.w) + bf2f(c.w));
    }
    *(ushort4*)(kvb + (size_t)p*256 + ci) = o;
}

// ---------------------------------------------------------------- implicit-GEMM conv v6
// Block = (row-pair rp, dy, co-half ch): 64*5*2 = 640 blocks, 4 waves = co-eighths.
// Per wave per iter: 4 A-frags (LDS, 2 rows x 2 mtiles) + 2 B-frags (global)
// -> 16 MFMA per 2 B-frags: round-7 B-reuse ratio at round-8 TLP (2.5 waves/SIMD).
__global__ __launch_bounds__(256) void conv_mfma5(
    const ushort* __restrict__ kvb, const ushort* __restrict__ wct,
    float* __restrict__ pconv)
{
    __shared__ __align__(16) ushort Arows[2][9504];  // 36 pos x 264 (28 filled + overrun)
    int tid = threadIdx.x;
    int bid = blockIdx.x;                 // ((rp*5 + dy)<<1) | ch
    int ch = bid & 1;
    int t2 = bid >> 1;
    int rp = t2 / 5, dy = t2 - rp*5;
    int b = rp >> 5, y0 = (rp & 31)*2;

    const ushort* src0 = kvb + ((size_t)((b*68 + y0 + dy)*28))*256;
    const ushort* src1 = kvb + ((size_t)((b*68 + y0 + 1 + dy)*28))*256;
    #pragma unroll
    for (int i = 0; i < 7; ++i) {
        int c = i*256 + tid;              // 1792 chunks of 8
        int row = (c >= 896);
        int cc = c - row*896;
        int pos = cc >> 5, off = (cc & 31)*8;
        *(bf16x8*)(&Arows[row][pos*264 + off]) =
            *(const bf16x8*)((row ? src1 : src0) + (size_t)(pos*256 + off));
    }
    __syncthreads();

    int w = tid >> 6;                     // co-eighth within the half
    int lane = tid & 63, lm = lane & 15, lq = lane >> 4;
    const ushort* bbase = wct + ((size_t)((dy*5)*256 + ch*128 + w*32 + lm))*256 + lq*8;
    const ushort* a00 = &Arows[0][lm*264 + lq*8];

    f32x4 acc[2][2][2];
    #pragma unroll
    for (int r = 0; r < 2; ++r)
        #pragma unroll
        for (int mt = 0; mt < 2; ++mt)
            #pragma unroll
            for (int nt = 0; nt < 2; ++nt)
                acc[r][mt][nt] = (f32x4){0.f,0.f,0.f,0.f};

    // depth-2 rolling B prefetch (2 frags per slot)
    bf16x8 b0[2], b1[2];
    #pragma unroll
    for (int nt = 0; nt < 2; ++nt) b0[nt] = *(const bf16x8*)(bbase + nt*4096);
    #pragma unroll
    for (int nt = 0; nt < 2; ++nt) b1[nt] = *(const bf16x8*)(bbase + 32 + nt*4096);

    for (int iter = 0; iter < 40; ++iter) {          // iter = dx*8 + chk
        int i2 = (iter + 2 < 40) ? iter + 2 : 39;
        int boff = (i2 >> 3)*65536 + (i2 & 7)*32;
        bf16x8 bn[2];
        #pragma unroll
        for (int nt = 0; nt < 2; ++nt) bn[nt] = *(const bf16x8*)(bbase + boff + nt*4096);

        int aoff = (iter >> 3)*264 + (iter & 7)*32;  // dx*264 + chk*32
        bf16x8 af[2][2];
        #pragma unroll
        for (int r = 0; r < 2; ++r)
            #pragma unroll
            for (int mt = 0; mt < 2; ++mt)
                af[r][mt] = *(const bf16x8*)(a00 + r*9504 + mt*4224 + aoff);

        #pragma unroll
        for (int r = 0; r < 2; ++r)
            #pragma unroll
            for (int mt = 0; mt < 2; ++mt)
                #pragma unroll
                for (int nt = 0; nt < 2; ++nt)
                    acc[r][mt][nt] = __builtin_amdgcn_mfma_f32_16x16x32_bf16(
                        af[r][mt], b0[nt], acc[r][mt][nt], 0, 0, 0);

        #pragma unroll
        for (int nt = 0; nt < 2; ++nt) { b0[nt] = b1[nt]; b1[nt] = bn[nt]; }
    }

    #pragma unroll
    for (int r = 0; r < 2; ++r) {
        int grow = rp*2 + r;
        #pragma unroll
        for (int mt = 0; mt < 2; ++mt) {
            #pragma unroll
            for (int nt = 0; nt < 2; ++nt) {
                int cob = ch*128 + w*32 + nt*16 + lm;
                #pragma unroll
                for (int j = 0; j < 4; ++j) {
                    int x = mt*16 + lq*4 + j;
                    if (x < 24)
                        pconv[((size_t)(dy*3072 + grow*24 + x))*256 + cob]
                            = acc[r][mt][nt][j];
                }
            }
        }
    }
}

// ---------------------------------------------------------------- LN2 fused with dy-reduce
__global__ __launch_bounds__(256) void ln2_fused(
    const float* __restrict__ xr, const float* __restrict__ pc, const float* __restrict__ cb,
    const float* __restrict__ gamma, const float* __restrict__ beta,
    float* __restrict__ out)
{
    int pos  = blockIdx.x*4 + (threadIdx.x >> 6);
    int lane = threadIdx.x & 63;
    size_t base = (size_t)pos*256 + lane*4;
    float4 gsum = *(const float4*)(cb + lane*4);
    #pragma unroll
    for (int d = 0; d < 5; ++d) {
        float4 v = *(const float4*)(pc + (size_t)d*NE + base);
        gsum.x += v.x; gsum.y += v.y; gsum.z += v.z; gsum.w += v.w;
    }
    float4 a = *(const float4*)(xr + base);
    float x0 = a.x + gsum.x, x1 = a.y + gsum.y, x2 = a.z + gsum.z, x3 = a.w + gsum.w;
    float s  = x0 + x1 + x2 + x3;
    float sq = x0*x0 + x1*x1 + x2*x2 + x3*x3;
    #pragma unroll
    for (int off = 32; off > 0; off >>= 1) {
        s  += __shfl_xor(s,  off);
        sq += __shfl_xor(sq, off);
    }
    float mean = s * (1.0f/256.0f);
    float var  = sq * (1.0f/256.0f) - mean*mean;
    float rstd = rsqrtf(var + 1e-5f);
    float4 gv = *(const float4*)(gamma + lane*4);
    float4 bv = *(const float4*)(beta  + lane*4);
    float4 o;
    o.x = (x0 - mean)*rstd*gv.x + bv.x;
    o.y = (x1 - mean)*rstd*gv.y + bv.y;
    o.z = (x2 - mean)*rstd*gv.z + bv.z;
    o.w = (x3 - mean)*rstd*gv.w + bv.w;
    *(float4*)(out + base) = o;
}

// ---------------------------------------------------------------- launcher
extern "C" void kernel_launch(void* const* d_in, const int* in_sizes, int n_in,
                              void* d_out, int out_size, void* d_ws, size_t ws_size,
                              hipStream_t stream)
{
    (void)in_sizes; (void)n_in; (void)out_size; (void)ws_size;
    const float* x    = (const float*)d_in[0];
    const float* wq   = (const float*)d_in[1];
    const float* bq   = (const float*)d_in[2];
    const float* wk   = (const float*)d_in[3];
    const float* bk   = (const float*)d_in[4];
    const float* wv   = (const float*)d_in[5];
    const float* bv   = (const float*)d_in[6];
    const float* wqa  = (const float*)d_in[7];
    const float* bqa  = (const float*)d_in[8];
    const float* wka  = (const float*)d_in[9];
    const float* bka  = (const float*)d_in[10];
    const float* wva  = (const float*)d_in[11];
    const float* bva  = (const float*)d_in[12];
    const float* woa  = (const float*)d_in[13];
    const float* boa  = (const float*)d_in[14];
    const float* cw   = (const float*)d_in[15];
    const float* cbi  = (const float*)d_in[16];
    const float* ln1g = (const float*)d_in[17];
    const float* ln1b = (const float*)d_in[18];
    const float* ln2g = (const float*)d_in[19];
    const float* ln2b = (const float*)d_in[20];
    float* out = (float*)d_out;

    float* ws = (float*)d_ws;
    const size_t HNE = NE/2;
    ushort* qpb = (ushort*)(ws + 0*HNE);
    ushort* kpb = (ushort*)(ws + 1*HNE);
    ushort* xb  = (ushort*)(ws + 2*HNE);   // slot used as x_res (fp32)
    ushort* vpb = (ushort*)(ws + 3*HNE);
    ushort* qab = (ushort*)(ws + 4*HNE);
    ushort* kab = (ushort*)(ws + 5*HNE);
    ushort* vab = (ushort*)(ws + 6*HNE);
    float* R    = ws + 8*HNE;              // 3,932,160 floats
    float* pacc = R;
    float* pl   = R + 3145728;
    float* pconv= R;                       // reuses R after gemm_wo_ln consumed pacc/pl
    ushort* wt7 = (ushort*)(R + 3932160);
    ushort* wct = (ushort*)(R + 3932160 + 229376);
    ushort* kvb = (ushort*)(R + 3932160 + 229376 + 819200);
    float* qloc = R + 3932160 + 229376 + 819200 + 487424;
    float* kloc = qloc + 4096;
    int*   Rix  = (int*)(kloc + 4096);
    float* x_res = (float*)xb;

    // 1. weight preps
    wtrans7<<<dim3(16,7), 256, 0, stream>>>(wq,wk,wv,wqa,wka,wva,woa, wt7);
    wtrans<<<400, 256, 0, stream>>>(cw, wct);
    // 2. routing (fused mean+projection, fp32 exact) + top-k
    qkloc2<<<dim3(16,2), 256, 0, stream>>>(x, wq,bq, wk,bk, qloc, kloc);
    topk_kern<<<2, 64, 0, stream>>>(qloc, kloc, Rix);
    // 3. q/k/v projections (bf16 MFMA)
    gemm_btx3<<<dim3(96,3), 256, 0, stream>>>(
        x, wt7, wt7+65536, wt7+131072, bq,bk,bv, qpb,kpb,vpb);
    // 4. conv input (bf16)
    addkv_pad2<<<952, 256, 0, stream>>>(kpb, vpb, kvb);
    // 5. attention projections (qab pre-scaled by 1/sqrt(dk))
    gemm_bt3<<<dim3(96,3), 256, 0, stream>>>(
        qpb,kpb,vpb, wt7+196608, wt7+262144, wt7+327680, bqa,bka,bva,
        qab,kab,vab, 0.17677669529663687f,1.f,1.f);
    // 6. MFMA flash attention (inline V-transpose)
    attn_mfma2<<<dim3(128,4), 256, 0, stream>>>(qab, kab, vab, Rix, pl, pacc);
    // 7. wo projection fused with merge + LN1 -> x_res
    gemm_wo_ln<<<96, 256, 0, stream>>>(pl, pacc, wt7+393216, boa, x, ln1g, ln1b, x_res);
    // 8. conv v6 (co-split grid: round-7 B-reuse at round-8 TLP)
    conv_mfma5<<<640, 256, 0, stream>>>(kvb, wct, pconv);
    // 9. LN2 fused with dy-reduce + bias -> out
    ln2_fused<<<NPOS/4, 256, 0, stream>>>(x_res, pconv, cbi, ln2g, ln2b, out);
}

// Round 10
// 205.926 us; speedup vs baseline: 1.1418x; 1.0299x over previous
//
#include <hip/hip_runtime.h>
#include <hip/hip_bf16.h>

// DRSA temporal block. B=2, P=8, hp=8, W=24, C=256, NH=8, dk=32, kv=4, H=64.
// 3072 positions, [pos][256] row-major. All GEMM-shaped work on bf16 MFMA.
// 9 dispatches: wtransA, qkloc2, topk, gemm_btx3, gemm_bt3, attn_mfma2,
// gemm_wo_ln, conv_mfma6 (inline pad, bf16 partials), ln2_fused.

#define NPOS 3072
#define CD   256
#define NE   (NPOS*CD)

typedef short bf16x8 __attribute__((ext_vector_type(8)));
typedef float f32x4  __attribute__((ext_vector_type(4)));

__device__ inline ushort f2bf(float f) {
    __hip_bfloat16 h = __float2bfloat16(f);   // RNE
    return *reinterpret_cast<ushort*>(&h);
}
__device__ inline float bf2f(ushort u) {
    unsigned v = ((unsigned)u) << 16;
    return *reinterpret_cast<float*>(&v);
}
// bf16 lane-wise add with RNE re-round (identical to old addkv_pad2 arithmetic)
__device__ inline bf16x8 addbf(bf16x8 a, bf16x8 b) {
    bf16x8 o;
    #pragma unroll
    for (int j = 0; j < 8; ++j)
        o[j] = (short)f2bf(bf2f((ushort)a[j]) + bf2f((ushort)b[j]));
    return o;
}

// ---------------------------------------------------------------- all 8 weight transposes
// blk<112: dense mats (7 x 16 tiles) -> wt[mat][n][k]; else conv taps (25 x 16) -> wct.
__global__ __launch_bounds__(256) void wtransA(
    const float* __restrict__ w0, const float* __restrict__ w1, const float* __restrict__ w2,
    const float* __restrict__ w3, const float* __restrict__ w4, const float* __restrict__ w5,
    const float* __restrict__ w6, const float* __restrict__ cw,
    ushort* __restrict__ wt, ushort* __restrict__ wct)
{
    __shared__ float l[64*65];
    int blk = blockIdx.x;            // 0..511
    const float* M;
    ushort* D;
    int r2;
    if (blk < 112) {
        int mat = blk >> 4; r2 = blk & 15;
        M = mat==0?w0:mat==1?w1:mat==2?w2:mat==3?w3:mat==4?w4:mat==5?w5:w6;
        D = wt + (size_t)mat*65536;
    } else {
        int b2 = blk - 112;
        int tap = b2 >> 4; r2 = b2 & 15;
        M = cw + (size_t)tap*65536;
        D = wct + (size_t)tap*65536;
    }
    int ci0 = (r2 >> 2)*64, co0 = (r2 & 3)*64;
    int tid = threadIdx.x, a = tid >> 6, c = tid & 63;
    #pragma unroll 4
    for (int k = 0; k < 16; ++k) {
        int cil = k*4 + a;
        l[cil*65 + c] = M[(size_t)(ci0 + cil)*256 + co0 + c];
    }
    __syncthreads();
    #pragma unroll 4
    for (int k = 0; k < 16; ++k) {
        int col = k*4 + a;
        D[((size_t)(co0 + col))*256 + ci0 + c] = f2bf(l[c*65 + col]);
    }
}

// ---------------------------------------------------------------- fused xmean + q/k_loc [fp32 exact]
__global__ __launch_bounds__(256) void qkloc2(
    const float* __restrict__ x,
    const float* __restrict__ wq, const float* __restrict__ bq,
    const float* __restrict__ wk, const float* __restrict__ bk,
    float* __restrict__ qloc, float* __restrict__ kloc)
{
    __shared__ float xs[256];
    int bp = blockIdx.x, c = threadIdx.x;
    float s = 0.f;
    for (int i = 0; i < 192; ++i)
        s += x[((size_t)(bp*192 + i))*256 + c];
    xs[c] = s * (1.0f/192.0f);
    __syncthreads();
    const float* W  = blockIdx.y ? wk : wq;
    const float* Bv = blockIdx.y ? bk : bq;
    float* dst      = blockIdx.y ? kloc : qloc;
    float acc = Bv[c];
    #pragma unroll 8
    for (int k = 0; k < 256; ++k)
        acc += xs[k] * W[(size_t)k*256 + c];
    dst[bp*256 + c] = acc;
}

// ---------------------------------------------------------------- routing top-k (fp32 exact)
__global__ void topk_kern(const float* __restrict__ qloc, const float* __restrict__ kloc,
                          int* __restrict__ Rix)
{
    __shared__ float S[64];
    int b = blockIdx.x, t = threadIdx.x;
    int p = t >> 3, qq = t & 7;
    float s = 0.f;
    for (int c = 0; c < 256; ++c)
        s += qloc[(b*8+p)*256 + c] * kloc[(b*8+qq)*256 + c];
    S[t] = s;
    __syncthreads();
    if (t < 8) {
        float vals[8];
        #pragma unroll
        for (int j = 0; j < 8; ++j) vals[j] = S[t*8 + j];
        for (int j = 0; j < 4; ++j) {
            int best = 0; float bv = vals[0];
            #pragma unroll
            for (int i = 1; i < 8; ++i) if (vals[i] > bv) { bv = vals[i]; best = i; }
            Rix[(b*8 + t)*4 + j] = best;
            vals[best] = -1e30f;
        }
    }
}

// ---------------------------------------------------------------- bf16 MFMA GEMM triple, fp32 A
__global__ __launch_bounds__(256) void gemm_btx3(
    const float* __restrict__ A,
    const ushort* __restrict__ T0, const ushort* __restrict__ T1, const ushort* __restrict__ T2,
    const float* __restrict__ B0, const float* __restrict__ B1, const float* __restrict__ B2,
    ushort* __restrict__ U0, ushort* __restrict__ U1, ushort* __restrict__ U2)
{
    __shared__ __align__(16) ushort As[32*264];
    int y = blockIdx.y;
    const ushort* T = y==0 ? T0 : (y==1 ? T1 : T2);
    const float* Bi = y==0 ? B0 : (y==1 ? B1 : B2);
    ushort* U = y==0 ? U0 : (y==1 ? U1 : U2);
    int tid = threadIdx.x;
    int m0 = blockIdx.x*32;
    #pragma unroll
    for (int i = 0; i < 4; ++i) {
        int c = i*256 + tid;
        int pos = c >> 5, off = (c & 31)*8;
        const float* src = A + (size_t)(m0 + pos)*256 + off;
        float4 v0 = *(const float4*)src;
        float4 v1 = *(const float4*)(src + 4);
        ushort4 o0, o1;
        o0.x = f2bf(v0.x); o0.y = f2bf(v0.y); o0.z = f2bf(v0.z); o0.w = f2bf(v0.w);
        o1.x = f2bf(v1.x); o1.y = f2bf(v1.y); o1.z = f2bf(v1.z); o1.w = f2bf(v1.w);
        *(ushort4*)&As[pos*264 + off]     = o0;
        *(ushort4*)&As[pos*264 + off + 4] = o1;
    }
    __syncthreads();
    int w = tid >> 6, lane = tid & 63, lm = lane & 15, lq = lane >> 4;
    const ushort* tb = T + ((size_t)(w*64 + lm))*256 + lq*8;

    f32x4 acc[2][4];
    #pragma unroll
    for (int mt = 0; mt < 2; ++mt)
        #pragma unroll
        for (int nt = 0; nt < 4; ++nt) acc[mt][nt] = (f32x4){0.f,0.f,0.f,0.f};

    bf16x8 bw[4];
    #pragma unroll
    for (int nt = 0; nt < 4; ++nt) bw[nt] = *(const bf16x8*)(tb + nt*4096);

    for (int kc = 0; kc < 8; ++kc) {
        int nk = (kc + 1 < 8) ? kc + 1 : 7;
        bf16x8 bn[4];
        #pragma unroll
        for (int nt = 0; nt < 4; ++nt) bn[nt] = *(const bf16x8*)(tb + nt*4096 + nk*32);
        bf16x8 af[2];
        #pragma unroll
        for (int mt = 0; mt < 2; ++mt)
            af[mt] = *(const bf16x8*)&As[(mt*16 + lm)*264 + kc*32 + lq*8];
        #pragma unroll
        for (int mt = 0; mt < 2; ++mt)
            #pragma unroll
            for (int nt = 0; nt < 4; ++nt)
                acc[mt][nt] = __builtin_amdgcn_mfma_f32_16x16x32_bf16(af[mt], bw[nt], acc[mt][nt], 0,0,0);
        #pragma unroll
        for (int nt = 0; nt < 4; ++nt) bw[nt] = bn[nt];
    }

    #pragma unroll
    for (int mt = 0; mt < 2; ++mt) {
        #pragma unroll
        for (int nt = 0; nt < 4; ++nt) {
            int n = w*64 + nt*16 + lm;
            float bb = Bi[n];
            #pragma unroll
            for (int j = 0; j < 4; ++j) {
                int m = m0 + mt*16 + lq*4 + j;
                U[(size_t)m*256 + n] = f2bf(acc[mt][nt][j] + bb);
            }
        }
    }
}

// ---------------------------------------------------------------- bf16 MFMA GEMM triple, bf16 A
__global__ __launch_bounds__(256) void gemm_bt3(
    const ushort* __restrict__ A0, const ushort* __restrict__ A1, const ushort* __restrict__ A2,
    const ushort* __restrict__ T0, const ushort* __restrict__ T1, const ushort* __restrict__ T2,
    const float* __restrict__ B0, const float* __restrict__ B1, const float* __restrict__ B2,
    ushort* __restrict__ U0, ushort* __restrict__ U1, ushort* __restrict__ U2,
    float s0, float s1, float s2)
{
    __shared__ __align__(16) ushort As[32*264];
    int y = blockIdx.y;
    const ushort* A = y==0 ? A0 : (y==1 ? A1 : A2);
    const ushort* T = y==0 ? T0 : (y==1 ? T1 : T2);
    const float* Bi = y==0 ? B0 : (y==1 ? B1 : B2);
    ushort* U = y==0 ? U0 : (y==1 ? U1 : U2);
    float  sc = y==0 ? s0 : (y==1 ? s1 : s2);
    int tid = threadIdx.x;
    int m0 = blockIdx.x*32;
    #pragma unroll
    for (int i = 0; i < 4; ++i) {
        int c = i*256 + tid;
        int pos = c >> 5, off = (c & 31)*8;
        *(bf16x8*)&As[pos*264 + off] = *(const bf16x8*)(A + (size_t)(m0 + pos)*256 + off);
    }
    __syncthreads();
    int w = tid >> 6, lane = tid & 63, lm = lane & 15, lq = lane >> 4;
    const ushort* tb = T + ((size_t)(w*64 + lm))*256 + lq*8;

    f32x4 acc[2][4];
    #pragma unroll
    for (int mt = 0; mt < 2; ++mt)
        #pragma unroll
        for (int nt = 0; nt < 4; ++nt) acc[mt][nt] = (f32x4){0.f,0.f,0.f,0.f};

    bf16x8 bw[4];
    #pragma unroll
    for (int nt = 0; nt < 4; ++nt) bw[nt] = *(const bf16x8*)(tb + nt*4096);

    for (int kc = 0; kc < 8; ++kc) {
        int nk = (kc + 1 < 8) ? kc + 1 : 7;
        bf16x8 bn[4];
        #pragma unroll
        for (int nt = 0; nt < 4; ++nt) bn[nt] = *(const bf16x8*)(tb + nt*4096 + nk*32);
        bf16x8 af[2];
        #pragma unroll
        for (int mt = 0; mt < 2; ++mt)
            af[mt] = *(const bf16x8*)&As[(mt*16 + lm)*264 + kc*32 + lq*8];
        #pragma unroll
        for (int mt = 0; mt < 2; ++mt)
            #pragma unroll
            for (int nt = 0; nt < 4; ++nt)
                acc[mt][nt] = __builtin_amdgcn_mfma_f32_16x16x32_bf16(af[mt], bw[nt], acc[mt][nt], 0,0,0);
        #pragma unroll
        for (int nt = 0; nt < 4; ++nt) bw[nt] = bn[nt];
    }

    #pragma unroll
    for (int mt = 0; mt < 2; ++mt) {
        #pragma unroll
        for (int nt = 0; nt < 4; ++nt) {
            int n = w*64 + nt*16 + lm;
            float bb = Bi[n];
            #pragma unroll
            for (int j = 0; j < 4; ++j) {
                int m = m0 + mt*16 + lq*4 + j;
                U[(size_t)m*256 + n] = f2bf((acc[mt][nt][j] + bb) * sc);
            }
        }
    }
}

// ---------------------------------------------------------------- MFMA flash attention, inline V-T
// pacc now bf16 (partials pre-normalization; ~0.4% relative rounding, negligible after /l).
__global__ __launch_bounds__(256) void attn_mfma2(
    const ushort* __restrict__ qab, const ushort* __restrict__ kab,
    const ushort* __restrict__ vab, const int* __restrict__ Rix,
    float* __restrict__ pl, ushort* __restrict__ pacc)
{
    __shared__ ushort P[4][16*40];
    __shared__ ushort Vs[32*200];     // [dk][key], stride 200
    int tid = threadIdx.x, w = tid >> 6, lane = tid & 63;
    int lm = lane & 15, lq = lane >> 4;
    int bph = blockIdx.x, kvb = blockIdx.y;
    int bp = bph >> 3, h = bph & 7, b = bp >> 3;
    int r = Rix[bp*4 + kvb];
    int vrow0 = (b*8 + r)*192;

    #pragma unroll
    for (int i = 0; i < 6; ++i) {
        int idx = i*256 + tid;
        int pos = idx >> 3, c4 = (idx & 7)*4;
        ushort4 v = *(const ushort4*)(vab + ((size_t)(vrow0 + pos))*256 + h*32 + c4);
        Vs[(c4+0)*200 + pos] = v.x;
        Vs[(c4+1)*200 + pos] = v.y;
        Vs[(c4+2)*200 + pos] = v.z;
        Vs[(c4+3)*200 + pos] = v.w;
    }

    bf16x8 qf[3];
    #pragma unroll
    for (int t = 0; t < 3; ++t)
        qf[t] = *(const bf16x8*)(qab + ((size_t)(bp*192 + w*48 + t*16 + lm))*256 + h*32 + lq*8);

    const ushort* kbase = kab + ((size_t)(vrow0))*256 + h*32 + lq*8;
    ushort* pw = P[w];
    __syncthreads();

    f32x4 O[3][2];
    #pragma unroll
    for (int t = 0; t < 3; ++t) { O[t][0] = (f32x4){0,0,0,0}; O[t][1] = (f32x4){0,0,0,0}; }
    float l[3] = {0.f, 0.f, 0.f};

    for (int k0 = 0; k0 < 192; k0 += 32) {
        bf16x8 kf0 = *(const bf16x8*)(kbase + (size_t)(k0 + lm)*256);
        bf16x8 kf1 = *(const bf16x8*)(kbase + (size_t)(k0 + 16 + lm)*256);
        bf16x8 vf0 = *(const bf16x8*)(&Vs[lm*200 + k0 + lq*8]);
        bf16x8 vf1 = *(const bf16x8*)(&Vs[(16 + lm)*200 + k0 + lq*8]);
        #pragma unroll
        for (int t = 0; t < 3; ++t) {
            f32x4 s0 = __builtin_amdgcn_mfma_f32_16x16x32_bf16(kf0, qf[t], (f32x4){0,0,0,0}, 0,0,0);
            f32x4 s1 = __builtin_amdgcn_mfma_f32_16x16x32_bf16(kf1, qf[t], (f32x4){0,0,0,0}, 0,0,0);
            float p0[4], p1[4];
            #pragma unroll
            for (int j = 0; j < 4; ++j) { p0[j] = __expf(s0[j]); p1[j] = __expf(s1[j]); }
            l[t] += p0[0]+p0[1]+p0[2]+p0[3] + p1[0]+p1[1]+p1[2]+p1[3];
            ushort4 a, c;
            a.x = f2bf(p0[0]); a.y = f2bf(p0[1]); a.z = f2bf(p0[2]); a.w = f2bf(p0[3]);
            c.x = f2bf(p1[0]); c.y = f2bf(p1[1]); c.z = f2bf(p1[2]); c.w = f2bf(p1[3]);
            *(ushort4*)(pw + lm*40 + lq*4)      = a;
            *(ushort4*)(pw + lm*40 + 16 + lq*4) = c;
            bf16x8 pf = *(const bf16x8*)(pw + lm*40 + lq*8);
            O[t][0] = __builtin_amdgcn_mfma_f32_16x16x32_bf16(pf, vf0, O[t][0], 0,0,0);
            O[t][1] = __builtin_amdgcn_mfma_f32_16x16x32_bf16(pf, vf1, O[t][1], 0,0,0);
        }
    }

    #pragma unroll
    for (int t = 0; t < 3; ++t) {
        float lt = l[t];
        lt += __shfl_xor(lt, 16);
        lt += __shfl_xor(lt, 32);
        size_t pbase = ((size_t)(bph*4 + kvb))*192 + w*48 + t*16;
        if (lq == 0) pl[pbase + lm] = lt;
        #pragma unroll
        for (int nt = 0; nt < 2; ++nt)
            #pragma unroll
            for (int reg = 0; reg < 4; ++reg)
                pacc[(pbase + lq*4 + reg)*32 + nt*16 + lm] = f2bf(O[t][nt][reg]);
    }
}

// ---------------------------------------------------------------- wo projection, fused merge + LN1
__global__ __launch_bounds__(256) void gemm_wo_ln(
    const float* __restrict__ pl, const ushort* __restrict__ pacc,
    const ushort* __restrict__ T, const float* __restrict__ boa,
    const float* __restrict__ x,
    const float* __restrict__ g1, const float* __restrict__ b1,
    float* __restrict__ x_res)
{
    __shared__ __align__(16) ushort As[32*264];
    __shared__ float L2x[32*256];
    int tid = threadIdx.x;
    int m0 = blockIdx.x*32;
    #pragma unroll
    for (int i = 0; i < 4; ++i) {
        int c = i*256 + tid;
        int pos = c >> 5, off = (c & 31)*8;
        int m = m0 + pos;
        int bp = m / 192, q = m - bp*192;
        int h = off >> 5, d0 = off & 31;
        int bph = bp*8 + h;
        float ls = 0.f;
        float cv[8] = {0,0,0,0,0,0,0,0};
        #pragma unroll
        for (int k = 0; k < 4; ++k) {
            size_t pidx = ((size_t)(bph*4 + k))*192 + q;
            ls += pl[pidx];
            bf16x8 pv = *(const bf16x8*)(pacc + pidx*32 + d0);
            #pragma unroll
            for (int j = 0; j < 8; ++j) cv[j] += bf2f((ushort)pv[j]);
        }
        ushort o[8];
        #pragma unroll
        for (int j = 0; j < 8; ++j) o[j] = f2bf(cv[j] / ls);
        *(ushort4*)&As[pos*264 + off]     = make_ushort4(o[0],o[1],o[2],o[3]);
        *(ushort4*)&As[pos*264 + off + 4] = make_ushort4(o[4],o[5],o[6],o[7]);
    }
    __syncthreads();
    int w = tid >> 6, lane = tid & 63, lm = lane & 15, lq = lane >> 4;
    const ushort* tb = T + ((size_t)(w*64 + lm))*256 + lq*8;

    f32x4 acc[2][4];
    #pragma unroll
    for (int mt = 0; mt < 2; ++mt)
        #pragma unroll
        for (int nt = 0; nt < 4; ++nt) acc[mt][nt] = (f32x4){0.f,0.f,0.f,0.f};

    bf16x8 bw[4];
    #pragma unroll
    for (int nt = 0; nt < 4; ++nt) bw[nt] = *(const bf16x8*)(tb + nt*4096);

    for (int kc = 0; kc < 8; ++kc) {
        int nk = (kc + 1 < 8) ? kc + 1 : 7;
        bf16x8 bn[4];
        #pragma unroll
        for (int nt = 0; nt < 4; ++nt) bn[nt] = *(const bf16x8*)(tb + nt*4096 + nk*32);
        bf16x8 af[2];
        #pragma unroll
        for (int mt = 0; mt < 2; ++mt)
            af[mt] = *(const bf16x8*)&As[(mt*16 + lm)*264 + kc*32 + lq*8];
        #pragma unroll
        for (int mt = 0; mt < 2; ++mt)
            #pragma unroll
            for (int nt = 0; nt < 4; ++nt)
                acc[mt][nt] = __builtin_amdgcn_mfma_f32_16x16x32_bf16(af[mt], bw[nt], acc[mt][nt], 0,0,0);
        #pragma unroll
        for (int nt = 0; nt < 4; ++nt) bw[nt] = bn[nt];
    }

    #pragma unroll
    for (int mt = 0; mt < 2; ++mt) {
        #pragma unroll
        for (int nt = 0; nt < 4; ++nt) {
            int n = w*64 + nt*16 + lm;
            float bb = boa[n];
            #pragma unroll
            for (int j = 0; j < 4; ++j) {
                int pos = mt*16 + lq*4 + j;
                float val = acc[mt][nt][j] + bb;
                L2x[pos*256 + n] = val + x[(size_t)(m0 + pos)*256 + n];
            }
        }
    }
    __syncthreads();
    #pragma unroll
    for (int rr = 0; rr < 8; ++rr) {
        int pos = w*8 + rr;
        float4 a = *(const float4*)(&L2x[pos*256 + lane*4]);
        float x0 = a.x, x1 = a.y, x2 = a.z, x3 = a.w;
        float s  = x0 + x1 + x2 + x3;
        float sq = x0*x0 + x1*x1 + x2*x2 + x3*x3;
        #pragma unroll
        for (int off = 32; off > 0; off >>= 1) {
            s  += __shfl_xor(s,  off);
            sq += __shfl_xor(sq, off);
        }
        float mean = s * (1.0f/256.0f);
        float var  = sq * (1.0f/256.0f) - mean*mean;
        float rstd = rsqrtf(var + 1e-5f);
        float4 gv = *(const float4*)(g1 + lane*4);
        float4 bv = *(const float4*)(b1 + lane*4);
        float4 o;
        o.x = (x0 - mean)*rstd*gv.x + bv.x;
        o.y = (x1 - mean)*rstd*gv.y + bv.y;
        o.z = (x2 - mean)*rstd*gv.z + bv.z;
        o.w = (x3 - mean)*rstd*gv.w + bv.w;
        *(float4*)(x_res + (size_t)(m0 + pos)*256 + lane*4) = o;
    }
}

// ---------------------------------------------------------------- implicit-GEMM conv v7
// Round-9 structure (block=(row-pair,dy,co-half), 640 blocks, co-eighth waves,
// depth-2 B prefetch) + (a) inline halo-pad staging: reads k_p/v_p bf16 directly,
// adds with the same f2bf(bf2f+bf2f) rounding addkv_pad2 used (bit-identical values,
// recomputed per dy-block); (b) bf16 partial outputs (halves pconv traffic).
__global__ __launch_bounds__(256) void conv_mfma6(
    const ushort* __restrict__ kpb, const ushort* __restrict__ vpb,
    const ushort* __restrict__ wct, ushort* __restrict__ pconv)
{
    __shared__ __align__(16) ushort Arows[2][9504];  // 36 pos x 264 (28 filled + overrun)
    int tid = threadIdx.x;
    int bid = blockIdx.x;                 // ((rp*5 + dy)<<1) | ch
    int ch = bid & 1;
    int t2 = bid >> 1;
    int rp = t2 / 5, dy = t2 - rp*5;
    int b = rp >> 5, y0 = (rp & 31)*2;

    const bf16x8 zero8 = (bf16x8){0,0,0,0,0,0,0,0};
    #pragma unroll
    for (int i = 0; i < 7; ++i) {
        int c = i*256 + tid;              // 1792 chunks of 8
        int row = (c >= 896);
        int cc = c - row*896;
        int pos = cc >> 5, off = (cc & 31)*8;
        int y = y0 + row + dy - 2;        // padded row index minus halo
        bf16x8 v = zero8;
        if (y >= 0 && y < 64 && pos >= 2 && pos < 26) {
            size_t sb = ((size_t)((b*64 + y)*24 + (pos - 2)))*256 + off;
            v = addbf(*(const bf16x8*)(kpb + sb), *(const bf16x8*)(vpb + sb));
        }
        *(bf16x8*)(&Arows[row][pos*264 + off]) = v;
    }
    __syncthreads();

    int w = tid >> 6;                     // co-eighth within the half
    int lane = tid & 63, lm = lane & 15, lq = lane >> 4;
    const ushort* bbase = wct + ((size_t)((dy*5)*256 + ch*128 + w*32 + lm))*256 + lq*8;
    const ushort* a00 = &Arows[0][lm*264 + lq*8];

    f32x4 acc[2][2][2];
    #pragma unroll
    for (int r = 0; r < 2; ++r)
        #pragma unroll
        for (int mt = 0; mt < 2; ++mt)
            #pragma unroll
            for (int nt = 0; nt < 2; ++nt)
                acc[r][mt][nt] = (f32x4){0.f,0.f,0.f,0.f};

    bf16x8 b0[2], b1[2];
    #pragma unroll
    for (int nt = 0; nt < 2; ++nt) b0[nt] = *(const bf16x8*)(bbase + nt*4096);
    #pragma unroll
    for (int nt = 0; nt < 2; ++nt) b1[nt] = *(const bf16x8*)(bbase + 32 + nt*4096);

    for (int iter = 0; iter < 40; ++iter) {          // iter = dx*8 + chk
        int i2 = (iter + 2 < 40) ? iter + 2 : 39;
        int boff = (i2 >> 3)*65536 + (i2 & 7)*32;
        bf16x8 bn[2];
        #pragma unroll
        for (int nt = 0; nt < 2; ++nt) bn[nt] = *(const bf16x8*)(bbase + boff + nt*4096);

        int aoff = (iter >> 3)*264 + (iter & 7)*32;  // dx*264 + chk*32
        bf16x8 af[2][2];
        #pragma unroll
        for (int r = 0; r < 2; ++r)
            #pragma unroll
            for (int mt = 0; mt < 2; ++mt)
                af[r][mt] = *(const bf16x8*)(a00 + r*9504 + mt*4224 + aoff);

        #pragma unroll
        for (int r = 0; r < 2; ++r)
            #pragma unroll
            for (int mt = 0; mt < 2; ++mt)
                #pragma unroll
                for (int nt = 0; nt < 2; ++nt)
                    acc[r][mt][nt] = __builtin_amdgcn_mfma_f32_16x16x32_bf16(
                        af[r][mt], b0[nt], acc[r][mt][nt], 0, 0, 0);

        #pragma unroll
        for (int nt = 0; nt < 2; ++nt) { b0[nt] = b1[nt]; b1[nt] = bn[nt]; }
    }

    #pragma unroll
    for (int r = 0; r < 2; ++r) {
        int grow = rp*2 + r;
        #pragma unroll
        for (int mt = 0; mt < 2; ++mt) {
            #pragma unroll
            for (int nt = 0; nt < 2; ++nt) {
                int cob = ch*128 + w*32 + nt*16 + lm;
                #pragma unroll
                for (int j = 0; j < 4; ++j) {
                    int x = mt*16 + lq*4 + j;
                    if (x < 24)
                        pconv[((size_t)(dy*3072 + grow*24 + x))*256 + cob]
                            = f2bf(acc[r][mt][nt][j]);
                }
            }
        }
    }
}

// ---------------------------------------------------------------- LN2 fused with dy-reduce (bf16 partials)
__global__ __launch_bounds__(256) void ln2_fused(
    const float* __restrict__ xr, const ushort* __restrict__ pc, const float* __restrict__ cb,
    const float* __restrict__ gamma, const float* __restrict__ beta,
    float* __restrict__ out)
{
    int pos  = blockIdx.x*4 + (threadIdx.x >> 6);
    int lane = threadIdx.x & 63;
    size_t base = (size_t)pos*256 + lane*4;
    float4 gsum = *(const float4*)(cb + lane*4);
    #pragma unroll
    for (int d = 0; d < 5; ++d) {
        ushort4 v = *(const ushort4*)(pc + (size_t)d*NE + base);
        gsum.x += bf2f(v.x); gsum.y += bf2f(v.y);
        gsum.z += bf2f(v.z); gsum.w += bf2f(v.w);
    }
    float4 a = *(const float4*)(xr + base);
    float x0 = a.x + gsum.x, x1 = a.y + gsum.y, x2 = a.z + gsum.z, x3 = a.w + gsum.w;
    float s  = x0 + x1 + x2 + x3;
    float sq = x0*x0 + x1*x1 + x2*x2 + x3*x3;
    #pragma unroll
    for (int off = 32; off > 0; off >>= 1) {
        s  += __shfl_xor(s,  off);
        sq += __shfl_xor(sq, off);
    }
    float mean = s * (1.0f/256.0f);
    float var  = sq * (1.0f/256.0f) - mean*mean;
    float rstd = rsqrtf(var + 1e-5f);
    float4 gv = *(const float4*)(gamma + lane*4);
    float4 bv = *(const float4*)(beta  + lane*4);
    float4 o;
    o.x = (x0 - mean)*rstd*gv.x + bv.x;
    o.y = (x1 - mean)*rstd*gv.y + bv.y;
    o.z = (x2 - mean)*rstd*gv.z + bv.z;
    o.w = (x3 - mean)*rstd*gv.w + bv.w;
    *(float4*)(out + base) = o;
}

// ---------------------------------------------------------------- launcher
extern "C" void kernel_launch(void* const* d_in, const int* in_sizes, int n_in,
                              void* d_out, int out_size, void* d_ws, size_t ws_size,
                              hipStream_t stream)
{
    (void)in_sizes; (void)n_in; (void)out_size; (void)ws_size;
    const float* x    = (const float*)d_in[0];
    const float* wq   = (const float*)d_in[1];
    const float* bq   = (const float*)d_in[2];
    const float* wk   = (const float*)d_in[3];
    const float* bk   = (const float*)d_in[4];
    const float* wv   = (const float*)d_in[5];
    const float* bv   = (const float*)d_in[6];
    const float* wqa  = (const float*)d_in[7];
    const float* bqa  = (const float*)d_in[8];
    const float* wka  = (const float*)d_in[9];
    const float* bka  = (const float*)d_in[10];
    const float* wva  = (const float*)d_in[11];
    const float* bva  = (const float*)d_in[12];
    const float* woa  = (const float*)d_in[13];
    const float* boa  = (const float*)d_in[14];
    const float* cw   = (const float*)d_in[15];
    const float* cbi  = (const float*)d_in[16];
    const float* ln1g = (const float*)d_in[17];
    const float* ln1b = (const float*)d_in[18];
    const float* ln2g = (const float*)d_in[19];
    const float* ln2b = (const float*)d_in[20];
    float* out = (float*)d_out;

    // Workspace (floats): 8 HNE slots + R(3,932,160) + wt7 + wct + qloc/kloc/Rix ~= 32.5 MB
    float* ws = (float*)d_ws;
    const size_t HNE = NE/2;
    ushort* qpb = (ushort*)(ws + 0*HNE);
    ushort* kpb = (ushort*)(ws + 1*HNE);   // alive until conv
    ushort* vpb = (ushort*)(ws + 3*HNE);   // alive until conv
    ushort* qab = (ushort*)(ws + 4*HNE);
    ushort* kab = (ushort*)(ws + 5*HNE);
    ushort* vab = (ushort*)(ws + 6*HNE);   // dead after attn -> x_res slots 6-7
    float* x_res = (float*)(ws + 6*HNE);   // NE floats over slots 6,7
    float* R    = ws + 8*HNE;              // 3,932,160 floats
    ushort* pacc = (ushort*)R;             // 3,145,728 bf16 = 1,572,864 f
    float*  pl   = R + 1572864;            // 98,304 f
    ushort* pconv= (ushort*)R;             // 3,932,160 bf16; aliases pacc/pl after wo_ln
    ushort* wt7 = (ushort*)(R + 3932160);
    ushort* wct = (ushort*)(R + 3932160 + 229376);
    float* qloc = R + 3932160 + 229376 + 819200;
    float* kloc = qloc + 4096;
    int*   Rix  = (int*)(kloc + 4096);

    // 1. all weight transposes (one dispatch)
    wtransA<<<512, 256, 0, stream>>>(wq,wk,wv,wqa,wka,wva,woa, cw, wt7, wct);
    // 2. routing (fused mean+projection, fp32 exact) + top-k
    qkloc2<<<dim3(16,2), 256, 0, stream>>>(x, wq,bq, wk,bk, qloc, kloc);
    topk_kern<<<2, 64, 0, stream>>>(qloc, kloc, Rix);
    // 3. q/k/v projections (bf16 MFMA)
    gemm_btx3<<<dim3(96,3), 256, 0, stream>>>(
        x, wt7, wt7+65536, wt7+131072, bq,bk,bv, qpb,kpb,vpb);
    // 4. attention projections (qab pre-scaled by 1/sqrt(dk))
    gemm_bt3<<<dim3(96,3), 256, 0, stream>>>(
        qpb,kpb,vpb, wt7+196608, wt7+262144, wt7+327680, bqa,bka,bva,
        qab,kab,vab, 0.17677669529663687f,1.f,1.f);
    // 5. MFMA flash attention (inline V-transpose, bf16 partials)
    attn_mfma2<<<dim3(128,4), 256, 0, stream>>>(qab, kab, vab, Rix, pl, pacc);
    // 6. wo projection fused with merge + LN1 -> x_res (slots 6-7)
    gemm_wo_ln<<<96, 256, 0, stream>>>(pl, pacc, wt7+393216, boa, x, ln1g, ln1b, x_res);
    // 7. conv v7 (inline pad from k_p/v_p, bf16 partials; pacc/pl dead)
    conv_mfma6<<<640, 256, 0, stream>>>(kpb, vpb, wct, pconv);
    // 8. LN2 fused with dy-reduce + bias -> out
    ln2_fused<<<NPOS/4, 256, 0, stream>>>(x_res, pconv, cbi, ln2g, ln2b, out);
}